// Round 1
// baseline (684.357 us; speedup 1.0000x reference)
//
#include <hip/hip_runtime.h>

#define DIM 128
#define LN_EPS 1e-5f

// ---------------- CSR build ----------------

__global__ void zero_i32(int* __restrict__ p, int n) {
    int i = blockIdx.x * 256 + threadIdx.x;
    if (i < n) p[i] = 0;
}

__global__ void count_deg(const int* __restrict__ dst, int E, int* __restrict__ counts) {
    int i = blockIdx.x * 256 + threadIdx.x;
    if (i < E) atomicAdd(&counts[dst[i]], 1);
}

__global__ __launch_bounds__(1024) void scan_build(const int* __restrict__ counts,
                                                   int* __restrict__ rowptr,
                                                   int* __restrict__ cursor,
                                                   float* __restrict__ dinv, int n) {
    __shared__ int buf[1024];
    __shared__ int carry_s;
    int tid = threadIdx.x;
    if (tid == 0) carry_s = 0;
    __syncthreads();
    for (int base = 0; base < n; base += 1024) {
        int v = (base + tid < n) ? counts[base + tid] : 0;
        buf[tid] = v;
        __syncthreads();
        for (int off = 1; off < 1024; off <<= 1) {
            int t = (tid >= off) ? buf[tid - off] : 0;
            __syncthreads();
            buf[tid] += t;
            __syncthreads();
        }
        int excl = buf[tid] - v;
        int carry = carry_s;
        if (base + tid < n) {
            rowptr[base + tid] = carry + excl;
            cursor[base + tid] = carry + excl;
            dinv[base + tid] = 1.0f / (float)((v > 1) ? v : 1);
        }
        __syncthreads();
        if (tid == 0) carry_s = carry + buf[1023];
        __syncthreads();
    }
    if (tid == 0) rowptr[n] = carry_s;
}

__global__ void fill_csr(const int* __restrict__ src, const int* __restrict__ dst, int E,
                         int* __restrict__ cursor, int* __restrict__ srcidx) {
    int i = blockIdx.x * 256 + threadIdx.x;
    if (i < E) {
        int p = atomicAdd(&cursor[dst[i]], 1);
        srcidx[p] = src[i];
    }
}

// ---------------- aggregation: m[n] = (1/deg) * sum_{e: dst=n} h[src[e]] ----------------
// one wave (64 lanes) per node; lane covers 2 dims (float2) -> coalesced 512B row reads

__global__ __launch_bounds__(256) void aggregate(const float* __restrict__ h,
                                                 const int* __restrict__ rowptr,
                                                 const int* __restrict__ srcidx,
                                                 const float* __restrict__ dinv,
                                                 float* __restrict__ m, int N) {
    int node = blockIdx.x * 4 + (threadIdx.x >> 6);
    if (node >= N) return;
    int lane = threadIdx.x & 63;
    int beg = rowptr[node], end = rowptr[node + 1];
    float ax = 0.f, ay = 0.f;
    for (int e = beg; e < end; ++e) {
        int s = srcidx[e];
        float2 v = *(const float2*)(h + (size_t)s * DIM + lane * 2);
        ax += v.x;
        ay += v.y;
    }
    float di = dinv[node];
    float2 o;
    o.x = ax * di;
    o.y = ay * di;
    *(float2*)(m + (size_t)node * DIM + lane * 2) = o;
}

// ---------------- GEMM tile helpers ----------------
// Block = 256 threads, tile = 64 rows x 128 cols. tx = tid&31 (4 cols each), ty = tid>>5
// (8 rows each, rows ty*8..ty*8+7). A tile staged in LDS; B (128x128) streamed from
// global (L1/L2-cached, broadcast across thread-rows).

#define TILE_ROWS 64

__device__ __forceinline__ void load_A_tile(const float* __restrict__ A, float4* As4,
                                            int r0, int N, int tid) {
#pragma unroll
    for (int i = 0; i < 8; ++i) {
        int idx = tid + i * 256;           // 2048 float4s = 64 rows * 32
        int r = idx >> 5, c = idx & 31;
        int gr = r0 + r;
        float4 v;
        if (gr < N)
            v = ((const float4*)A)[(size_t)gr * 32 + c];
        else
            v = make_float4(0.f, 0.f, 0.f, 0.f);
        As4[idx] = v;
    }
}

__device__ __forceinline__ void gemm_tile(const float4* __restrict__ As4,
                                          const float* __restrict__ W, int tx, int ty,
                                          float4 acc[8]) {
    const float4* Wv = (const float4*)W;
#pragma unroll
    for (int rr = 0; rr < 8; ++rr) acc[rr] = make_float4(0.f, 0.f, 0.f, 0.f);
    for (int k = 0; k < 128; k += 4) {
        float4 b0 = Wv[(k + 0) * 32 + tx];
        float4 b1 = Wv[(k + 1) * 32 + tx];
        float4 b2 = Wv[(k + 2) * 32 + tx];
        float4 b3 = Wv[(k + 3) * 32 + tx];
#pragma unroll
        for (int rr = 0; rr < 8; ++rr) {
            float4 a = As4[(ty * 8 + rr) * 32 + (k >> 2)];
            acc[rr].x += a.x * b0.x + a.y * b1.x + a.z * b2.x + a.w * b3.x;
            acc[rr].y += a.x * b0.y + a.y * b1.y + a.z * b2.y + a.w * b3.y;
            acc[rr].z += a.x * b0.z + a.y * b1.z + a.z * b2.z + a.w * b3.z;
            acc[rr].w += a.x * b0.w + a.y * b1.w + a.z * b2.w + a.w * b3.w;
        }
    }
}

// ---------------- input projection: h = x @ in_w + in_b ----------------

__global__ __launch_bounds__(256) void gemm_bias(const float* __restrict__ A,
                                                 const float* __restrict__ W,
                                                 const float* __restrict__ bias,
                                                 float* __restrict__ out, int N) {
    __shared__ float As[TILE_ROWS * 128];
    float4* As4 = (float4*)As;
    int tid = threadIdx.x;
    int tx = tid & 31, ty = tid >> 5;
    int r0 = blockIdx.x * TILE_ROWS;

    load_A_tile(A, As4, r0, N, tid);
    __syncthreads();

    float4 acc[8];
    gemm_tile(As4, W, tx, ty, acc);

    float4 bv = ((const float4*)bias)[tx];
#pragma unroll
    for (int rr = 0; rr < 8; ++rr) {
        int gr = r0 + ty * 8 + rr;
        if (gr < N) {
            float4 o;
            o.x = acc[rr].x + bv.x;
            o.y = acc[rr].y + bv.y;
            o.z = acc[rr].z + bv.z;
            o.w = acc[rr].w + bv.w;
            ((float4*)out)[(size_t)gr * 32 + tx] = o;
        }
    }
}

// ---------------- fused MLP + residual + LayerNorm ----------------
// h_out = LN(h_in + relu(m@W1+b1)@W2+b2)

__global__ __launch_bounds__(256) void mlp_ln(const float* __restrict__ m,
                                              const float* __restrict__ h_in,
                                              const float* __restrict__ W1,
                                              const float* __restrict__ B1,
                                              const float* __restrict__ W2,
                                              const float* __restrict__ B2,
                                              const float* __restrict__ G,
                                              const float* __restrict__ Bb,
                                              float* __restrict__ h_out, int N) {
    __shared__ float As[TILE_ROWS * 128];
    float4* As4 = (float4*)As;
    int tid = threadIdx.x;
    int tx = tid & 31, ty = tid >> 5;
    int r0 = blockIdx.x * TILE_ROWS;

    load_A_tile(m, As4, r0, N, tid);
    __syncthreads();

    float4 acc[8];
    gemm_tile(As4, W1, tx, ty, acc);

    // relu(acc + b1) back into LDS
    float4 b1v = ((const float4*)B1)[tx];
    __syncthreads();  // all reads of As done
#pragma unroll
    for (int rr = 0; rr < 8; ++rr) {
        float4 t;
        t.x = fmaxf(acc[rr].x + b1v.x, 0.f);
        t.y = fmaxf(acc[rr].y + b1v.y, 0.f);
        t.z = fmaxf(acc[rr].z + b1v.z, 0.f);
        t.w = fmaxf(acc[rr].w + b1v.w, 0.f);
        As4[(ty * 8 + rr) * 32 + tx] = t;
    }
    __syncthreads();

    gemm_tile(As4, W2, tx, ty, acc);

    float4 b2v = ((const float4*)B2)[tx];
    float4 gv = ((const float4*)G)[tx];
    float4 bbv = ((const float4*)Bb)[tx];

#pragma unroll
    for (int rr = 0; rr < 8; ++rr) {
        int gr = r0 + ty * 8 + rr;
        float4 hv = make_float4(0.f, 0.f, 0.f, 0.f);
        if (gr < N) hv = ((const float4*)h_in)[(size_t)gr * 32 + tx];
        float4 z;
        z.x = acc[rr].x + b2v.x + hv.x;
        z.y = acc[rr].y + b2v.y + hv.y;
        z.z = acc[rr].z + b2v.z + hv.z;
        z.w = acc[rr].w + b2v.w + hv.w;
        float s1 = z.x + z.y + z.z + z.w;
        float s2 = z.x * z.x + z.y * z.y + z.z * z.z + z.w * z.w;
        // reduce across the 32 lanes (same ty) that hold this row
#pragma unroll
        for (int off = 16; off > 0; off >>= 1) {
            s1 += __shfl_xor(s1, off, 32);
            s2 += __shfl_xor(s2, off, 32);
        }
        float mean = s1 * (1.0f / 128.0f);
        float var = s2 * (1.0f / 128.0f) - mean * mean;
        float rs = rsqrtf(var + LN_EPS);
        if (gr < N) {
            float4 o;
            o.x = (z.x - mean) * rs * gv.x + bbv.x;
            o.y = (z.y - mean) * rs * gv.y + bbv.y;
            o.z = (z.z - mean) * rs * gv.z + bbv.z;
            o.w = (z.w - mean) * rs * gv.w + bbv.w;
            ((float4*)h_out)[(size_t)gr * 32 + tx] = o;
        }
    }
}

// ---------------- launch ----------------

extern "C" void kernel_launch(void* const* d_in, const int* in_sizes, int n_in,
                              void* d_out, int out_size, void* d_ws, size_t ws_size,
                              hipStream_t stream) {
    const float* x    = (const float*)d_in[0];
    const int*   ei   = (const int*)d_in[1];
    const float* in_w = (const float*)d_in[2];
    const float* in_b = (const float*)d_in[3];
    const float* w1   = (const float*)d_in[4];
    const float* b1   = (const float*)d_in[5];
    const float* w2   = (const float*)d_in[6];
    const float* b2   = (const float*)d_in[7];
    const float* ln_g = (const float*)d_in[8];
    const float* ln_b = (const float*)d_in[9];

    const int N = in_sizes[0] / DIM;       // 50000
    const int E = in_sizes[1] / 2;         // 640000
    const int LAYERS = in_sizes[4] / (DIM * DIM);  // 3

    const int* e_src = ei;
    const int* e_dst = ei + E;

    // workspace layout
    char* ws = (char*)d_ws;
    float* h      = (float*)ws;                         ws += (size_t)N * DIM * 4;
    float* mbuf   = (float*)ws;                         ws += (size_t)N * DIM * 4;
    int*   counts = (int*)ws;                           ws += (size_t)N * 4;
    int*   rowptr = (int*)ws;                           ws += (size_t)(N + 1) * 4;
    int*   cursor = (int*)ws;                           ws += (size_t)N * 4;
    float* dinv   = (float*)ws;                         ws += (size_t)N * 4;
    int*   srcidx = (int*)ws;                           ws += (size_t)E * 4;

    // --- CSR build (once per call; deg is layer-invariant) ---
    zero_i32<<<(N + 255) / 256, 256, 0, stream>>>(counts, N);
    count_deg<<<(E + 255) / 256, 256, 0, stream>>>(e_dst, E, counts);
    scan_build<<<1, 1024, 0, stream>>>(counts, rowptr, cursor, dinv, N);
    fill_csr<<<(E + 255) / 256, 256, 0, stream>>>(e_src, e_dst, E, cursor, srcidx);

    // --- input projection ---
    int gemm_grid = (N + TILE_ROWS - 1) / TILE_ROWS;
    gemm_bias<<<gemm_grid, 256, 0, stream>>>(x, in_w, in_b, h, N);

    // --- layers ---
    for (int i = 0; i < LAYERS; ++i) {
        aggregate<<<(N + 3) / 4, 256, 0, stream>>>(h, rowptr, srcidx, dinv, mbuf, N);
        float* out = (i == LAYERS - 1) ? (float*)d_out : h;
        mlp_ln<<<gemm_grid, 256, 0, stream>>>(mbuf, h,
                                              w1 + (size_t)i * DIM * DIM, b1 + (size_t)i * DIM,
                                              w2 + (size_t)i * DIM * DIM, b2 + (size_t)i * DIM,
                                              ln_g + (size_t)i * DIM, ln_b + (size_t)i * DIM,
                                              out, N);
    }
}

// Round 2
// 602.494 us; speedup vs baseline: 1.1359x; 1.1359x over previous
//
#include <hip/hip_runtime.h>

#define DIM 128
#define LN_EPS 1e-5f

// ---------------- CSR build ----------------

__global__ void zero_i32(int* __restrict__ p, int n) {
    int i = blockIdx.x * 256 + threadIdx.x;
    if (i < n) p[i] = 0;
}

__global__ void count_deg(const int* __restrict__ dst, int E, int* __restrict__ counts) {
    int i = blockIdx.x * 256 + threadIdx.x;
    if (i < E) atomicAdd(&counts[dst[i]], 1);
}

// --- multi-block scan, step 1: per-block partial sums (1024 elems / block of 256) ---
__global__ __launch_bounds__(256) void scan_partials(const int* __restrict__ counts, int n,
                                                     int* __restrict__ bsum) {
    int base = blockIdx.x * 1024 + threadIdx.x * 4;
    int s = 0;
#pragma unroll
    for (int j = 0; j < 4; ++j) {
        int i = base + j;
        if (i < n) s += counts[i];
    }
    // wave-level reduce (64 lanes)
#pragma unroll
    for (int off = 32; off > 0; off >>= 1) s += __shfl_xor(s, off, 64);
    __shared__ int wsum[4];
    int lane = threadIdx.x & 63, wid = threadIdx.x >> 6;
    if (lane == 0) wsum[wid] = s;
    __syncthreads();
    if (threadIdx.x == 0) bsum[blockIdx.x] = wsum[0] + wsum[1] + wsum[2] + wsum[3];
}

// --- step 2: one wave scans the block sums (handles any nb via carry loop) ---
__global__ __launch_bounds__(64) void scan_bsums(const int* __restrict__ bsum,
                                                 int* __restrict__ bofs, int nb,
                                                 int* __restrict__ rowptr, int N, int E) {
    int lane = threadIdx.x;
    int carry = 0;
    for (int base = 0; base < nb; base += 64) {
        int v = (base + lane < nb) ? bsum[base + lane] : 0;
        int incl = v;
#pragma unroll
        for (int off = 1; off < 64; off <<= 1) {
            int t = __shfl_up(incl, off, 64);
            if (lane >= off) incl += t;
        }
        if (base + lane < nb) bofs[base + lane] = carry + incl - v;
        carry += __shfl(incl, 63, 64);
    }
    if (lane == 0) rowptr[N] = E;  // total edge count is known
}

// --- step 3: per-block scan with block offset; emit rowptr/cursor/dinv ---
__global__ __launch_bounds__(256) void scan_final(const int* __restrict__ counts, int n,
                                                  const int* __restrict__ bofs,
                                                  int* __restrict__ rowptr,
                                                  int* __restrict__ cursor,
                                                  float* __restrict__ dinv) {
    int base = blockIdx.x * 1024 + threadIdx.x * 4;
    int v[4];
#pragma unroll
    for (int j = 0; j < 4; ++j) {
        int i = base + j;
        v[j] = (i < n) ? counts[i] : 0;
    }
    int tsum = v[0] + v[1] + v[2] + v[3];
    int lane = threadIdx.x & 63, wid = threadIdx.x >> 6;
    int incl = tsum;
#pragma unroll
    for (int off = 1; off < 64; off <<= 1) {
        int t = __shfl_up(incl, off, 64);
        if (lane >= off) incl += t;
    }
    __shared__ int wsum[4];
    if (lane == 63) wsum[wid] = incl;
    __syncthreads();
    int wofs = 0;
    for (int w = 0; w < 4; ++w)
        if (w < wid) wofs += wsum[w];
    int excl = bofs[blockIdx.x] + wofs + (incl - tsum);
#pragma unroll
    for (int j = 0; j < 4; ++j) {
        int i = base + j;
        if (i < n) {
            rowptr[i] = excl;
            cursor[i] = excl;
            dinv[i] = 1.0f / (float)((v[j] > 1) ? v[j] : 1);
            excl += v[j];
        }
    }
}

__global__ void fill_csr(const int* __restrict__ src, const int* __restrict__ dst, int E,
                         int* __restrict__ cursor, int* __restrict__ srcidx) {
    int i = blockIdx.x * 256 + threadIdx.x;
    if (i < E) {
        int p = atomicAdd(&cursor[dst[i]], 1);
        srcidx[p] = src[i];
    }
}

// ---------------- aggregation: m[n] = (1/deg) * sum_{e: dst=n} h[src[e]] ----------------
// one wave (64 lanes) per node; lane covers 2 dims (float2) -> coalesced 512B row reads

__global__ __launch_bounds__(256) void aggregate(const float* __restrict__ h,
                                                 const int* __restrict__ rowptr,
                                                 const int* __restrict__ srcidx,
                                                 const float* __restrict__ dinv,
                                                 float* __restrict__ m, int N) {
    int node = blockIdx.x * 4 + (threadIdx.x >> 6);
    if (node >= N) return;
    int lane = threadIdx.x & 63;
    int beg = rowptr[node], end = rowptr[node + 1];
    float ax = 0.f, ay = 0.f;
    for (int e = beg; e < end; ++e) {
        int s = srcidx[e];
        float2 v = *(const float2*)(h + (size_t)s * DIM + lane * 2);
        ax += v.x;
        ay += v.y;
    }
    float di = dinv[node];
    float2 o;
    o.x = ax * di;
    o.y = ay * di;
    *(float2*)(m + (size_t)node * DIM + lane * 2) = o;
}

// ---------------- GEMM tile helpers ----------------
// Block = 256 threads, tile = 64 rows x 128 cols. tx = tid&31 (4 cols each), ty = tid>>5
// (8 rows each). A tile staged in LDS; B (128x128) streamed from global (L1/L2-cached).

#define TILE_ROWS 64

__device__ __forceinline__ void load_A_tile(const float* __restrict__ A, float4* As4,
                                            int r0, int N, int tid) {
#pragma unroll
    for (int i = 0; i < 8; ++i) {
        int idx = tid + i * 256;           // 2048 float4s = 64 rows * 32
        int r = idx >> 5, c = idx & 31;
        int gr = r0 + r;
        float4 v;
        if (gr < N)
            v = ((const float4*)A)[(size_t)gr * 32 + c];
        else
            v = make_float4(0.f, 0.f, 0.f, 0.f);
        As4[idx] = v;
    }
}

__device__ __forceinline__ void gemm_tile(const float4* __restrict__ As4,
                                          const float* __restrict__ W, int tx, int ty,
                                          float4 acc[8]) {
    const float4* Wv = (const float4*)W;
#pragma unroll
    for (int rr = 0; rr < 8; ++rr) acc[rr] = make_float4(0.f, 0.f, 0.f, 0.f);
    for (int k = 0; k < 128; k += 4) {
        float4 b0 = Wv[(k + 0) * 32 + tx];
        float4 b1 = Wv[(k + 1) * 32 + tx];
        float4 b2 = Wv[(k + 2) * 32 + tx];
        float4 b3 = Wv[(k + 3) * 32 + tx];
#pragma unroll
        for (int rr = 0; rr < 8; ++rr) {
            float4 a = As4[(ty * 8 + rr) * 32 + (k >> 2)];
            acc[rr].x += a.x * b0.x + a.y * b1.x + a.z * b2.x + a.w * b3.x;
            acc[rr].y += a.x * b0.y + a.y * b1.y + a.z * b2.y + a.w * b3.y;
            acc[rr].z += a.x * b0.z + a.y * b1.z + a.z * b2.z + a.w * b3.z;
            acc[rr].w += a.x * b0.w + a.y * b1.w + a.z * b2.w + a.w * b3.w;
        }
    }
}

// ---------------- input projection: h = x @ in_w + in_b ----------------

__global__ __launch_bounds__(256) void gemm_bias(const float* __restrict__ A,
                                                 const float* __restrict__ W,
                                                 const float* __restrict__ bias,
                                                 float* __restrict__ out, int N) {
    __shared__ float As[TILE_ROWS * 128];
    float4* As4 = (float4*)As;
    int tid = threadIdx.x;
    int tx = tid & 31, ty = tid >> 5;
    int r0 = blockIdx.x * TILE_ROWS;

    load_A_tile(A, As4, r0, N, tid);
    __syncthreads();

    float4 acc[8];
    gemm_tile(As4, W, tx, ty, acc);

    float4 bv = ((const float4*)bias)[tx];
#pragma unroll
    for (int rr = 0; rr < 8; ++rr) {
        int gr = r0 + ty * 8 + rr;
        if (gr < N) {
            float4 o;
            o.x = acc[rr].x + bv.x;
            o.y = acc[rr].y + bv.y;
            o.z = acc[rr].z + bv.z;
            o.w = acc[rr].w + bv.w;
            ((float4*)out)[(size_t)gr * 32 + tx] = o;
        }
    }
}

// ---------------- fused MLP + residual + LayerNorm ----------------
// h_out = LN(h_in + relu(m@W1+b1)@W2+b2)

__global__ __launch_bounds__(256) void mlp_ln(const float* __restrict__ m,
                                              const float* __restrict__ h_in,
                                              const float* __restrict__ W1,
                                              const float* __restrict__ B1,
                                              const float* __restrict__ W2,
                                              const float* __restrict__ B2,
                                              const float* __restrict__ G,
                                              const float* __restrict__ Bb,
                                              float* __restrict__ h_out, int N) {
    __shared__ float As[TILE_ROWS * 128];
    float4* As4 = (float4*)As;
    int tid = threadIdx.x;
    int tx = tid & 31, ty = tid >> 5;
    int r0 = blockIdx.x * TILE_ROWS;

    load_A_tile(m, As4, r0, N, tid);
    __syncthreads();

    float4 acc[8];
    gemm_tile(As4, W1, tx, ty, acc);

    // relu(acc + b1) back into LDS
    float4 b1v = ((const float4*)B1)[tx];
    __syncthreads();  // all reads of As done
#pragma unroll
    for (int rr = 0; rr < 8; ++rr) {
        float4 t;
        t.x = fmaxf(acc[rr].x + b1v.x, 0.f);
        t.y = fmaxf(acc[rr].y + b1v.y, 0.f);
        t.z = fmaxf(acc[rr].z + b1v.z, 0.f);
        t.w = fmaxf(acc[rr].w + b1v.w, 0.f);
        As4[(ty * 8 + rr) * 32 + tx] = t;
    }
    __syncthreads();

    gemm_tile(As4, W2, tx, ty, acc);

    float4 b2v = ((const float4*)B2)[tx];
    float4 gv = ((const float4*)G)[tx];
    float4 bbv = ((const float4*)Bb)[tx];

#pragma unroll
    for (int rr = 0; rr < 8; ++rr) {
        int gr = r0 + ty * 8 + rr;
        float4 hv = make_float4(0.f, 0.f, 0.f, 0.f);
        if (gr < N) hv = ((const float4*)h_in)[(size_t)gr * 32 + tx];
        float4 z;
        z.x = acc[rr].x + b2v.x + hv.x;
        z.y = acc[rr].y + b2v.y + hv.y;
        z.z = acc[rr].z + b2v.z + hv.z;
        z.w = acc[rr].w + b2v.w + hv.w;
        float s1 = z.x + z.y + z.z + z.w;
        float s2 = z.x * z.x + z.y * z.y + z.z * z.z + z.w * z.w;
        // reduce across the 32 lanes (same ty) that hold this row
#pragma unroll
        for (int off = 16; off > 0; off >>= 1) {
            s1 += __shfl_xor(s1, off, 32);
            s2 += __shfl_xor(s2, off, 32);
        }
        float mean = s1 * (1.0f / 128.0f);
        float var = s2 * (1.0f / 128.0f) - mean * mean;
        float rs = rsqrtf(var + LN_EPS);
        if (gr < N) {
            float4 o;
            o.x = (z.x - mean) * rs * gv.x + bbv.x;
            o.y = (z.y - mean) * rs * gv.y + bbv.y;
            o.z = (z.z - mean) * rs * gv.z + bbv.z;
            o.w = (z.w - mean) * rs * gv.w + bbv.w;
            ((float4*)h_out)[(size_t)gr * 32 + tx] = o;
        }
    }
}

// ---------------- launch ----------------

extern "C" void kernel_launch(void* const* d_in, const int* in_sizes, int n_in,
                              void* d_out, int out_size, void* d_ws, size_t ws_size,
                              hipStream_t stream) {
    const float* x    = (const float*)d_in[0];
    const int*   ei   = (const int*)d_in[1];
    const float* in_w = (const float*)d_in[2];
    const float* in_b = (const float*)d_in[3];
    const float* w1   = (const float*)d_in[4];
    const float* b1   = (const float*)d_in[5];
    const float* w2   = (const float*)d_in[6];
    const float* b2   = (const float*)d_in[7];
    const float* ln_g = (const float*)d_in[8];
    const float* ln_b = (const float*)d_in[9];

    const int N = in_sizes[0] / DIM;       // 50000
    const int E = in_sizes[1] / 2;         // 640000
    const int LAYERS = in_sizes[4] / (DIM * DIM);  // 3

    const int* e_src = ei;
    const int* e_dst = ei + E;

    // workspace layout
    char* ws = (char*)d_ws;
    float* h      = (float*)ws;                         ws += (size_t)N * DIM * 4;
    float* mbuf   = (float*)ws;                         ws += (size_t)N * DIM * 4;
    int*   counts = (int*)ws;                           ws += (size_t)N * 4;
    int*   rowptr = (int*)ws;                           ws += (size_t)(N + 1) * 4;
    int*   cursor = (int*)ws;                           ws += (size_t)N * 4;
    float* dinv   = (float*)ws;                         ws += (size_t)N * 4;
    int*   srcidx = (int*)ws;                           ws += (size_t)E * 4;
    int*   bsum   = (int*)ws;                           ws += 4096;
    int*   bofs   = (int*)ws;                           ws += 4096;

    const int nScanBlocks = (N + 1023) / 1024;

    // --- CSR build (once per call; deg is layer-invariant) ---
    zero_i32<<<(N + 255) / 256, 256, 0, stream>>>(counts, N);
    count_deg<<<(E + 255) / 256, 256, 0, stream>>>(e_dst, E, counts);
    scan_partials<<<nScanBlocks, 256, 0, stream>>>(counts, N, bsum);
    scan_bsums<<<1, 64, 0, stream>>>(bsum, bofs, nScanBlocks, rowptr, N, E);
    scan_final<<<nScanBlocks, 256, 0, stream>>>(counts, N, bofs, rowptr, cursor, dinv);
    fill_csr<<<(E + 255) / 256, 256, 0, stream>>>(e_src, e_dst, E, cursor, srcidx);

    // --- input projection ---
    int gemm_grid = (N + TILE_ROWS - 1) / TILE_ROWS;
    gemm_bias<<<gemm_grid, 256, 0, stream>>>(x, in_w, in_b, h, N);

    // --- layers ---
    for (int i = 0; i < LAYERS; ++i) {
        aggregate<<<(N + 3) / 4, 256, 0, stream>>>(h, rowptr, srcidx, dinv, mbuf, N);
        float* out = (i == LAYERS - 1) ? (float*)d_out : h;
        mlp_ln<<<gemm_grid, 256, 0, stream>>>(mbuf, h,
                                              w1 + (size_t)i * DIM * DIM, b1 + (size_t)i * DIM,
                                              w2 + (size_t)i * DIM * DIM, b2 + (size_t)i * DIM,
                                              ln_g + (size_t)i * DIM, ln_b + (size_t)i * DIM,
                                              out, N);
    }
}

// Round 3
// 511.191 us; speedup vs baseline: 1.3387x; 1.1786x over previous
//
#include <hip/hip_runtime.h>

#define DIM 128
#define LN_EPS 1e-5f

typedef __attribute__((ext_vector_type(8))) short s16x8;   // 8 bf16 in 4 VGPRs
typedef __attribute__((ext_vector_type(4))) float f32x4;

__device__ __forceinline__ unsigned short f2bf(float f) {
    unsigned u = __float_as_uint(f);
    unsigned r = u + 0x7fffu + ((u >> 16) & 1u);   // round-to-nearest-even
    return (unsigned short)(r >> 16);
}

// ---------------- CSR build ----------------

__global__ void zero_i32(int* __restrict__ p, int n) {
    int i = blockIdx.x * 256 + threadIdx.x;
    if (i < n) p[i] = 0;
}

__global__ void count_deg(const int* __restrict__ dst, int E, int* __restrict__ counts) {
    int i = blockIdx.x * 256 + threadIdx.x;
    if (i < E) atomicAdd(&counts[dst[i]], 1);
}

__global__ __launch_bounds__(256) void scan_partials(const int* __restrict__ counts, int n,
                                                     int* __restrict__ bsum) {
    int base = blockIdx.x * 1024 + threadIdx.x * 4;
    int s = 0;
#pragma unroll
    for (int j = 0; j < 4; ++j) {
        int i = base + j;
        if (i < n) s += counts[i];
    }
#pragma unroll
    for (int off = 32; off > 0; off >>= 1) s += __shfl_xor(s, off, 64);
    __shared__ int wsum[4];
    int lane = threadIdx.x & 63, wid = threadIdx.x >> 6;
    if (lane == 0) wsum[wid] = s;
    __syncthreads();
    if (threadIdx.x == 0) bsum[blockIdx.x] = wsum[0] + wsum[1] + wsum[2] + wsum[3];
}

__global__ __launch_bounds__(64) void scan_bsums(const int* __restrict__ bsum,
                                                 int* __restrict__ bofs, int nb,
                                                 int* __restrict__ rowptr, int N, int E) {
    int lane = threadIdx.x;
    int carry = 0;
    for (int base = 0; base < nb; base += 64) {
        int v = (base + lane < nb) ? bsum[base + lane] : 0;
        int incl = v;
#pragma unroll
        for (int off = 1; off < 64; off <<= 1) {
            int t = __shfl_up(incl, off, 64);
            if (lane >= off) incl += t;
        }
        if (base + lane < nb) bofs[base + lane] = carry + incl - v;
        carry += __shfl(incl, 63, 64);
    }
    if (lane == 0) rowptr[N] = E;
}

__global__ __launch_bounds__(256) void scan_final(const int* __restrict__ counts, int n,
                                                  const int* __restrict__ bofs,
                                                  int* __restrict__ rowptr,
                                                  int* __restrict__ cursor,
                                                  float* __restrict__ dinv) {
    int base = blockIdx.x * 1024 + threadIdx.x * 4;
    int v[4];
#pragma unroll
    for (int j = 0; j < 4; ++j) {
        int i = base + j;
        v[j] = (i < n) ? counts[i] : 0;
    }
    int tsum = v[0] + v[1] + v[2] + v[3];
    int lane = threadIdx.x & 63, wid = threadIdx.x >> 6;
    int incl = tsum;
#pragma unroll
    for (int off = 1; off < 64; off <<= 1) {
        int t = __shfl_up(incl, off, 64);
        if (lane >= off) incl += t;
    }
    __shared__ int wsum[4];
    if (lane == 63) wsum[wid] = incl;
    __syncthreads();
    int wofs = 0;
    for (int w = 0; w < 4; ++w)
        if (w < wid) wofs += wsum[w];
    int excl = bofs[blockIdx.x] + wofs + (incl - tsum);
#pragma unroll
    for (int j = 0; j < 4; ++j) {
        int i = base + j;
        if (i < n) {
            rowptr[i] = excl;
            cursor[i] = excl;
            dinv[i] = 1.0f / (float)((v[j] > 1) ? v[j] : 1);
            excl += v[j];
        }
    }
}

__global__ void fill_csr(const int* __restrict__ src, const int* __restrict__ dst, int E,
                         int* __restrict__ cursor, int* __restrict__ srcidx) {
    int i = blockIdx.x * 256 + threadIdx.x;
    if (i < E) {
        int p = atomicAdd(&cursor[dst[i]], 1);
        srcidx[p] = src[i];
    }
}

// ---------------- weight conversion: f32 row-major -> bf16 transposed ----------------
// mats: 0 = in_w, 1..L = w1[i], L+1..2L = w2[i]. 8 blocks per matrix.

__global__ __launch_bounds__(256) void cvt_weights(const float* __restrict__ in_w,
                                                   const float* __restrict__ w1,
                                                   const float* __restrict__ w2,
                                                   unsigned short* __restrict__ wt, int L) {
    int mat = blockIdx.x >> 3, part = blockIdx.x & 7;
    const float* src;
    if (mat == 0) src = in_w;
    else if (mat <= L) src = w1 + (size_t)(mat - 1) * DIM * DIM;
    else src = w2 + (size_t)(mat - 1 - L) * DIM * DIM;
    unsigned short* dst = wt + (size_t)mat * DIM * DIM;
    int base = part * 2048 + threadIdx.x;
#pragma unroll
    for (int j = 0; j < 8; ++j) {
        int i = base + j * 256;
        int k = i >> 7, n = i & 127;
        dst[n * DIM + k] = f2bf(src[i]);
    }
}

// ---------------- aggregation (bf16 gather): m[n] = (1/deg) * sum h_bf[src[e]] ----------------

__global__ __launch_bounds__(256) void aggregate(const unsigned short* __restrict__ hb,
                                                 const int* __restrict__ rowptr,
                                                 const int* __restrict__ srcidx,
                                                 const float* __restrict__ dinv,
                                                 unsigned short* __restrict__ m_bf, int N) {
    int node = blockIdx.x * 4 + (threadIdx.x >> 6);
    if (node >= N) return;
    int lane = threadIdx.x & 63;
    int beg = rowptr[node], end = rowptr[node + 1];
    float ax = 0.f, ay = 0.f;
    for (int e = beg; e < end; ++e) {
        int s = srcidx[e];
        unsigned v = *(const unsigned*)(hb + (size_t)s * DIM + lane * 2);
        ax += __uint_as_float(v << 16);
        ay += __uint_as_float(v & 0xffff0000u);
    }
    float di = dinv[node];
    unsigned o = (unsigned)f2bf(ax * di) | ((unsigned)f2bf(ay * di) << 16);
    *(unsigned*)(m_bf + (size_t)node * DIM + lane * 2) = o;
}

// ---------------- input projection (MFMA): h = x @ in_w + in_b ----------------
// block = 256 threads = 4 waves, 64 rows; wave handles 16 rows x 128 cols.

__global__ __launch_bounds__(256) void gemm_bias_mfma(const float* __restrict__ x,
                                                      const unsigned short* __restrict__ Wt,
                                                      const float* __restrict__ bias,
                                                      float* __restrict__ h,
                                                      unsigned short* __restrict__ hb, int N) {
    int tid = threadIdx.x;
    int wv = tid >> 6, lane = tid & 63;
    int quad = lane >> 4, l16 = lane & 15;
    int r0 = blockIdx.x * 64 + wv * 16;
    int arow = r0 + l16;
    bool avalid = arow < N;

    f32x4 acc[8];
#pragma unroll
    for (int c = 0; c < 8; ++c) acc[c] = (f32x4){0.f, 0.f, 0.f, 0.f};

    const float4* xp = (const float4*)(x + (size_t)arow * DIM) + quad * 2;
#pragma unroll
    for (int k0 = 0; k0 < 128; k0 += 32) {
        s16x8 a = {0, 0, 0, 0, 0, 0, 0, 0};
        if (avalid) {
            float4 f0 = xp[k0 / 4];
            float4 f1 = xp[k0 / 4 + 1];
            a[0] = (short)f2bf(f0.x); a[1] = (short)f2bf(f0.y);
            a[2] = (short)f2bf(f0.z); a[3] = (short)f2bf(f0.w);
            a[4] = (short)f2bf(f1.x); a[5] = (short)f2bf(f1.y);
            a[6] = (short)f2bf(f1.z); a[7] = (short)f2bf(f1.w);
        }
#pragma unroll
        for (int c = 0; c < 8; ++c) {
            s16x8 b = *(const s16x8*)(Wt + ((size_t)(c * 16 + l16) << 7) + quad * 8 + k0);
            acc[c] = __builtin_amdgcn_mfma_f32_16x16x32_bf16(a, b, acc[c], 0, 0, 0);
        }
    }

#pragma unroll
    for (int reg = 0; reg < 4; ++reg) {
        int grow = r0 + quad * 4 + reg;
        if (grow < N) {
#pragma unroll
            for (int c = 0; c < 8; ++c) {
                int col = c * 16 + l16;
                float o = acc[c][reg] + bias[col];
                h[(size_t)grow * DIM + col] = o;
                hb[(size_t)grow * DIM + col] = f2bf(o);
            }
        }
    }
}

// ---------------- fused MLP + residual + LayerNorm (MFMA) ----------------
// h_out = LN(h_in + relu(m@W1+b1)@W2+b2); also emits bf16 copy for next aggregate.

__global__ __launch_bounds__(256) void mlp_ln_mfma(const unsigned short* __restrict__ m_bf,
                                                   const float* __restrict__ h_in,
                                                   const unsigned short* __restrict__ W1t,
                                                   const float* __restrict__ B1,
                                                   const unsigned short* __restrict__ W2t,
                                                   const float* __restrict__ B2,
                                                   const float* __restrict__ G,
                                                   const float* __restrict__ Bb,
                                                   float* __restrict__ h_out,
                                                   unsigned short* __restrict__ hb_out, int N) {
    __shared__ unsigned short P[64][136];   // +8 pad: spreads banks for A-frag b128 reads
    int tid = threadIdx.x;
    int wv = tid >> 6, lane = tid & 63;
    int quad = lane >> 4, l16 = lane & 15;
    int r0 = blockIdx.x * 64 + wv * 16;
    int arow = r0 + l16;
    bool avalid = arow < N;

    // ---- GEMM1: relu(m @ W1 + b1) ----
    f32x4 acc[8];
#pragma unroll
    for (int c = 0; c < 8; ++c) acc[c] = (f32x4){0.f, 0.f, 0.f, 0.f};

    const unsigned short* aptr = m_bf + ((size_t)arow << 7) + quad * 8;
#pragma unroll
    for (int k0 = 0; k0 < 128; k0 += 32) {
        s16x8 a = {0, 0, 0, 0, 0, 0, 0, 0};
        if (avalid) a = *(const s16x8*)(aptr + k0);
#pragma unroll
        for (int c = 0; c < 8; ++c) {
            s16x8 b = *(const s16x8*)(W1t + ((size_t)(c * 16 + l16) << 7) + quad * 8 + k0);
            acc[c] = __builtin_amdgcn_mfma_f32_16x16x32_bf16(a, b, acc[c], 0, 0, 0);
        }
    }

#pragma unroll
    for (int c = 0; c < 8; ++c) {
        float bv = B1[c * 16 + l16];
#pragma unroll
        for (int reg = 0; reg < 4; ++reg) {
            float v = fmaxf(acc[c][reg] + bv, 0.f);
            P[wv * 16 + quad * 4 + reg][c * 16 + l16] = f2bf(v);
        }
    }
    __syncthreads();

    // ---- GEMM2: P @ W2 ----
#pragma unroll
    for (int c = 0; c < 8; ++c) acc[c] = (f32x4){0.f, 0.f, 0.f, 0.f};

    const unsigned short* pptr = &P[wv * 16 + l16][quad * 8];
#pragma unroll
    for (int k0 = 0; k0 < 128; k0 += 32) {
        s16x8 a = *(const s16x8*)(pptr + k0);
#pragma unroll
        for (int c = 0; c < 8; ++c) {
            s16x8 b = *(const s16x8*)(W2t + ((size_t)(c * 16 + l16) << 7) + quad * 8 + k0);
            acc[c] = __builtin_amdgcn_mfma_f32_16x16x32_bf16(a, b, acc[c], 0, 0, 0);
        }
    }

    // ---- epilogue: residual + LN ----
    float b2v[8], gv[8], bbv[8];
#pragma unroll
    for (int c = 0; c < 8; ++c) {
        int col = c * 16 + l16;
        b2v[c] = B2[col];
        gv[c] = G[col];
        bbv[c] = Bb[col];
    }

#pragma unroll
    for (int reg = 0; reg < 4; ++reg) {
        int grow = r0 + quad * 4 + reg;
        bool rv = grow < N;
        float z[8];
        float s1 = 0.f, s2 = 0.f;
#pragma unroll
        for (int c = 0; c < 8; ++c) {
            float hv = rv ? h_in[((size_t)grow << 7) + c * 16 + l16] : 0.f;
            z[c] = acc[c][reg] + b2v[c] + hv;
            s1 += z[c];
            s2 += z[c] * z[c];
        }
        // reduce across the 16 lanes (fixed quad) holding this row
#pragma unroll
        for (int off = 1; off < 16; off <<= 1) {
            s1 += __shfl_xor(s1, off, 64);
            s2 += __shfl_xor(s2, off, 64);
        }
        float mean = s1 * (1.0f / 128.0f);
        float var = s2 * (1.0f / 128.0f) - mean * mean;
        float rs = rsqrtf(var + LN_EPS);
        if (rv) {
#pragma unroll
            for (int c = 0; c < 8; ++c) {
                int col = c * 16 + l16;
                float o = (z[c] - mean) * rs * gv[c] + bbv[c];
                h_out[((size_t)grow << 7) + col] = o;
                hb_out[((size_t)grow << 7) + col] = f2bf(o);
            }
        }
    }
}

// ---------------- launch ----------------

extern "C" void kernel_launch(void* const* d_in, const int* in_sizes, int n_in,
                              void* d_out, int out_size, void* d_ws, size_t ws_size,
                              hipStream_t stream) {
    const float* x    = (const float*)d_in[0];
    const int*   ei   = (const int*)d_in[1];
    const float* in_w = (const float*)d_in[2];
    const float* in_b = (const float*)d_in[3];
    const float* w1   = (const float*)d_in[4];
    const float* b1   = (const float*)d_in[5];
    const float* w2   = (const float*)d_in[6];
    const float* b2   = (const float*)d_in[7];
    const float* ln_g = (const float*)d_in[8];
    const float* ln_b = (const float*)d_in[9];

    const int N = in_sizes[0] / DIM;               // 50000
    const int E = in_sizes[1] / 2;                 // 640000
    const int LAYERS = in_sizes[4] / (DIM * DIM);  // 3

    const int* e_src = ei;
    const int* e_dst = ei + E;

    // workspace layout
    char* ws = (char*)d_ws;
    float*          h      = (float*)ws;           ws += (size_t)N * DIM * 4;
    unsigned short* hb     = (unsigned short*)ws;  ws += (size_t)N * DIM * 2;
    unsigned short* m_bf   = (unsigned short*)ws;  ws += (size_t)N * DIM * 2;
    int*            counts = (int*)ws;             ws += (size_t)N * 4;
    int*            rowptr = (int*)ws;             ws += (size_t)(N + 1) * 4;
    int*            cursor = (int*)ws;             ws += (size_t)N * 4;
    float*          dinv   = (float*)ws;           ws += (size_t)N * 4;
    int*            srcidx = (int*)ws;             ws += (size_t)E * 4;
    int*            bsum   = (int*)ws;             ws += 4096;
    int*            bofs   = (int*)ws;             ws += 4096;
    unsigned short* wt     = (unsigned short*)ws;  ws += (size_t)(2 * LAYERS + 1) * DIM * DIM * 2;

    const int nScanBlocks = (N + 1023) / 1024;
    const int nMat = 2 * LAYERS + 1;

    // --- CSR build (deg is layer-invariant) + weight conversion ---
    zero_i32<<<(N + 255) / 256, 256, 0, stream>>>(counts, N);
    count_deg<<<(E + 255) / 256, 256, 0, stream>>>(e_dst, E, counts);
    scan_partials<<<nScanBlocks, 256, 0, stream>>>(counts, N, bsum);
    scan_bsums<<<1, 64, 0, stream>>>(bsum, bofs, nScanBlocks, rowptr, N, E);
    scan_final<<<nScanBlocks, 256, 0, stream>>>(counts, N, bofs, rowptr, cursor, dinv);
    fill_csr<<<(E + 255) / 256, 256, 0, stream>>>(e_src, e_dst, E, cursor, srcidx);
    cvt_weights<<<nMat * 8, 256, 0, stream>>>(in_w, w1, w2, wt, LAYERS);

    const unsigned short* in_wt = wt;
    const unsigned short* w1t   = wt + (size_t)DIM * DIM;
    const unsigned short* w2t   = wt + (size_t)(1 + LAYERS) * DIM * DIM;

    // --- input projection ---
    int gemm_grid = (N + 63) / 64;
    gemm_bias_mfma<<<gemm_grid, 256, 0, stream>>>(x, in_wt, in_b, h, hb, N);

    // --- layers ---
    for (int i = 0; i < LAYERS; ++i) {
        aggregate<<<(N + 3) / 4, 256, 0, stream>>>(hb, rowptr, srcidx, dinv, m_bf, N);
        float* out = (i == LAYERS - 1) ? (float*)d_out : h;
        mlp_ln_mfma<<<gemm_grid, 256, 0, stream>>>(m_bf, h,
                                                   w1t + (size_t)i * DIM * DIM, b1 + (size_t)i * DIM,
                                                   w2t + (size_t)i * DIM * DIM, b2 + (size_t)i * DIM,
                                                   ln_g + (size_t)i * DIM, ln_b + (size_t)i * DIM,
                                                   out, hb, N);
    }
}

// Round 4
// 438.720 us; speedup vs baseline: 1.5599x; 1.1652x over previous
//
#include <hip/hip_runtime.h>

#define DIM 128
#define LN_EPS 1e-5f

typedef __attribute__((ext_vector_type(8))) short s16x8;   // 8 bf16 in 4 VGPRs
typedef __attribute__((ext_vector_type(4))) float f32x4;
typedef __attribute__((ext_vector_type(4))) unsigned int u32x4;

__device__ __forceinline__ unsigned short f2bf(float f) {
    unsigned u = __float_as_uint(f);
    unsigned r = u + 0x7fffu + ((u >> 16) & 1u);   // round-to-nearest-even
    return (unsigned short)(r >> 16);
}
__device__ __forceinline__ float bf2f(unsigned short b) {
    return __uint_as_float(((unsigned)b) << 16);
}

// ---------------- CSR build ----------------

__global__ void count_deg(const int* __restrict__ dst, int E, int* __restrict__ counts) {
    int i = blockIdx.x * 256 + threadIdx.x;
    if (i < E) atomicAdd(&counts[dst[i]], 1);
}

__global__ __launch_bounds__(256) void scan_partials(const int* __restrict__ counts, int n,
                                                     int* __restrict__ bsum) {
    int base = blockIdx.x * 1024 + threadIdx.x * 4;
    int s = 0;
#pragma unroll
    for (int j = 0; j < 4; ++j) {
        int i = base + j;
        if (i < n) s += counts[i];
    }
#pragma unroll
    for (int off = 32; off > 0; off >>= 1) s += __shfl_xor(s, off, 64);
    __shared__ int wsum[4];
    int lane = threadIdx.x & 63, wid = threadIdx.x >> 6;
    if (lane == 0) wsum[wid] = s;
    __syncthreads();
    if (threadIdx.x == 0) bsum[blockIdx.x] = wsum[0] + wsum[1] + wsum[2] + wsum[3];
}

__global__ __launch_bounds__(64) void scan_bsums(const int* __restrict__ bsum,
                                                 int* __restrict__ bofs, int nb,
                                                 int* __restrict__ rowptr, int N, int E) {
    int lane = threadIdx.x;
    int carry = 0;
    for (int base = 0; base < nb; base += 64) {
        int v = (base + lane < nb) ? bsum[base + lane] : 0;
        int incl = v;
#pragma unroll
        for (int off = 1; off < 64; off <<= 1) {
            int t = __shfl_up(incl, off, 64);
            if (lane >= off) incl += t;
        }
        if (base + lane < nb) bofs[base + lane] = carry + incl - v;
        carry += __shfl(incl, 63, 64);
    }
    if (lane == 0) rowptr[N] = E;
}

__global__ __launch_bounds__(256) void scan_final(const int* __restrict__ counts, int n,
                                                  const int* __restrict__ bofs,
                                                  int* __restrict__ rowptr,
                                                  int* __restrict__ cursor,
                                                  float* __restrict__ dinv) {
    int base = blockIdx.x * 1024 + threadIdx.x * 4;
    int v[4];
#pragma unroll
    for (int j = 0; j < 4; ++j) {
        int i = base + j;
        v[j] = (i < n) ? counts[i] : 0;
    }
    int tsum = v[0] + v[1] + v[2] + v[3];
    int lane = threadIdx.x & 63, wid = threadIdx.x >> 6;
    int incl = tsum;
#pragma unroll
    for (int off = 1; off < 64; off <<= 1) {
        int t = __shfl_up(incl, off, 64);
        if (lane >= off) incl += t;
    }
    __shared__ int wsum[4];
    if (lane == 63) wsum[wid] = incl;
    __syncthreads();
    int wofs = 0;
    for (int w = 0; w < 4; ++w)
        if (w < wid) wofs += wsum[w];
    int excl = bofs[blockIdx.x] + wofs + (incl - tsum);
#pragma unroll
    for (int j = 0; j < 4; ++j) {
        int i = base + j;
        if (i < n) {
            rowptr[i] = excl;
            cursor[i] = excl;
            dinv[i] = 1.0f / (float)((v[j] > 1) ? v[j] : 1);
            excl += v[j];
        }
    }
}

__global__ void fill_csr(const int* __restrict__ src, const int* __restrict__ dst, int E,
                         int* __restrict__ cursor, int* __restrict__ srcidx) {
    int i = blockIdx.x * 256 + threadIdx.x;
    if (i < E) {
        int p = atomicAdd(&cursor[dst[i]], 1);
        srcidx[p] = src[i];
    }
}

// ---------------- weight conversion: f32 row-major -> bf16 transposed ----------------

__global__ __launch_bounds__(256) void cvt_weights(const float* __restrict__ in_w,
                                                   const float* __restrict__ w1,
                                                   const float* __restrict__ w2,
                                                   unsigned short* __restrict__ wt, int L) {
    int mat = blockIdx.x >> 3, part = blockIdx.x & 7;
    const float* src;
    if (mat == 0) src = in_w;
    else if (mat <= L) src = w1 + (size_t)(mat - 1) * DIM * DIM;
    else src = w2 + (size_t)(mat - 1 - L) * DIM * DIM;
    unsigned short* dst = wt + (size_t)mat * DIM * DIM;
    int base = part * 2048 + threadIdx.x;
#pragma unroll
    for (int j = 0; j < 8; ++j) {
        int i = base + j * 256;
        int k = i >> 7, n = i & 127;
        dst[n * DIM + k] = f2bf(src[i]);
    }
}

// ---------------- aggregation: 4 nodes per wave, 16 lanes x 16B per row ----------------
// m[n] = (1/deg) * sum_{e: dst=n} h_bf[src[e]]; ILP: edge loop unrolled x4, 2 acc sets.

__device__ __forceinline__ void acc_row(float* a, const unsigned short* __restrict__ hb,
                                        int s, int l) {
    u32x4 v = *(const u32x4*)(hb + ((size_t)s << 7) + l * 8);
#pragma unroll
    for (int i = 0; i < 4; ++i) {
        a[2 * i]     += __uint_as_float(v[i] << 16);
        a[2 * i + 1] += __uint_as_float(v[i] & 0xffff0000u);
    }
}

__global__ __launch_bounds__(256) void aggregate(const unsigned short* __restrict__ hb,
                                                 const int* __restrict__ rowptr,
                                                 const int* __restrict__ srcidx,
                                                 const float* __restrict__ dinv,
                                                 unsigned short* __restrict__ m_bf, int N) {
    int node = blockIdx.x * 16 + (threadIdx.x >> 4);   // 16 nodes per 256-thread block
    int l = threadIdx.x & 15;
    bool nvalid = node < N;
    int beg = nvalid ? rowptr[node] : 0;
    int end = nvalid ? rowptr[node + 1] : 0;

    float a0[8] = {0, 0, 0, 0, 0, 0, 0, 0};
    float a1[8] = {0, 0, 0, 0, 0, 0, 0, 0};

    int e = beg;
    while (__any(e < end)) {
        if (e < end)     { acc_row(a0, hb, srcidx[e],     l); }
        if (e + 1 < end) { acc_row(a1, hb, srcidx[e + 1], l); }
        if (e + 2 < end) { acc_row(a0, hb, srcidx[e + 2], l); }
        if (e + 3 < end) { acc_row(a1, hb, srcidx[e + 3], l); }
        e += 4;
    }

    if (nvalid) {
        float di = dinv[node];
        u32x4 o;
#pragma unroll
        for (int i = 0; i < 4; ++i) {
            unsigned lo = f2bf((a0[2 * i]     + a1[2 * i])     * di);
            unsigned hi = f2bf((a0[2 * i + 1] + a1[2 * i + 1]) * di);
            o[i] = lo | (hi << 16);
        }
        *(u32x4*)(m_bf + ((size_t)node << 7) + l * 8) = o;
    }
}

// ---------------- input projection (MFMA): hb = bf16(x @ in_w + in_b) ----------------

__global__ __launch_bounds__(256) void gemm_bias_mfma(const float* __restrict__ x,
                                                      const unsigned short* __restrict__ Wt,
                                                      const float* __restrict__ bias,
                                                      unsigned short* __restrict__ hb, int N) {
    int tid = threadIdx.x;
    int wv = tid >> 6, lane = tid & 63;
    int quad = lane >> 4, l16 = lane & 15;
    int r0 = blockIdx.x * 64 + wv * 16;
    int arow = r0 + l16;
    bool avalid = arow < N;

    f32x4 acc[8];
#pragma unroll
    for (int c = 0; c < 8; ++c) acc[c] = (f32x4){0.f, 0.f, 0.f, 0.f};

    const float4* xp = (const float4*)(x + (size_t)arow * DIM) + quad * 2;
#pragma unroll
    for (int k0 = 0; k0 < 128; k0 += 32) {
        s16x8 a = {0, 0, 0, 0, 0, 0, 0, 0};
        if (avalid) {
            float4 f0 = xp[k0 / 4];
            float4 f1 = xp[k0 / 4 + 1];
            a[0] = (short)f2bf(f0.x); a[1] = (short)f2bf(f0.y);
            a[2] = (short)f2bf(f0.z); a[3] = (short)f2bf(f0.w);
            a[4] = (short)f2bf(f1.x); a[5] = (short)f2bf(f1.y);
            a[6] = (short)f2bf(f1.z); a[7] = (short)f2bf(f1.w);
        }
#pragma unroll
        for (int c = 0; c < 8; ++c) {
            s16x8 b = *(const s16x8*)(Wt + ((size_t)(c * 16 + l16) << 7) + quad * 8 + k0);
            acc[c] = __builtin_amdgcn_mfma_f32_16x16x32_bf16(a, b, acc[c], 0, 0, 0);
        }
    }

#pragma unroll
    for (int reg = 0; reg < 4; ++reg) {
        int grow = r0 + quad * 4 + reg;
        if (grow < N) {
#pragma unroll
            for (int c = 0; c < 8; ++c) {
                int col = c * 16 + l16;
                hb[((size_t)grow << 7) + col] = f2bf(acc[c][reg] + bias[col]);
            }
        }
    }
}

// ---------------- fused MLP + residual + LayerNorm (MFMA) ----------------
// hb <- bf16(LN(hb + relu(m@W1+b1)@W2+b2)) in place; optionally write f32 to out.

__global__ __launch_bounds__(256) void mlp_ln_mfma(const unsigned short* __restrict__ m_bf,
                                                   unsigned short* __restrict__ hb,
                                                   const unsigned short* __restrict__ W1t,
                                                   const float* __restrict__ B1,
                                                   const unsigned short* __restrict__ W2t,
                                                   const float* __restrict__ B2,
                                                   const float* __restrict__ G,
                                                   const float* __restrict__ Bb,
                                                   float* __restrict__ out_f32, int N) {
    __shared__ unsigned short P[64][136];   // +8 pad
    int tid = threadIdx.x;
    int wv = tid >> 6, lane = tid & 63;
    int quad = lane >> 4, l16 = lane & 15;
    int r0 = blockIdx.x * 64 + wv * 16;
    int arow = r0 + l16;
    bool avalid = arow < N;

    // ---- GEMM1: relu(m @ W1 + b1) ----
    f32x4 acc[8];
#pragma unroll
    for (int c = 0; c < 8; ++c) acc[c] = (f32x4){0.f, 0.f, 0.f, 0.f};

    const unsigned short* aptr = m_bf + ((size_t)arow << 7) + quad * 8;
#pragma unroll
    for (int k0 = 0; k0 < 128; k0 += 32) {
        s16x8 a = {0, 0, 0, 0, 0, 0, 0, 0};
        if (avalid) a = *(const s16x8*)(aptr + k0);
#pragma unroll
        for (int c = 0; c < 8; ++c) {
            s16x8 b = *(const s16x8*)(W1t + ((size_t)(c * 16 + l16) << 7) + quad * 8 + k0);
            acc[c] = __builtin_amdgcn_mfma_f32_16x16x32_bf16(a, b, acc[c], 0, 0, 0);
        }
    }

#pragma unroll
    for (int c = 0; c < 8; ++c) {
        float bv = B1[c * 16 + l16];
#pragma unroll
        for (int reg = 0; reg < 4; ++reg) {
            float v = fmaxf(acc[c][reg] + bv, 0.f);
            P[wv * 16 + quad * 4 + reg][c * 16 + l16] = f2bf(v);
        }
    }
    __syncthreads();

    // ---- GEMM2: P @ W2 ----
#pragma unroll
    for (int c = 0; c < 8; ++c) acc[c] = (f32x4){0.f, 0.f, 0.f, 0.f};

    const unsigned short* pptr = &P[wv * 16 + l16][quad * 8];
#pragma unroll
    for (int k0 = 0; k0 < 128; k0 += 32) {
        s16x8 a = *(const s16x8*)(pptr + k0);
#pragma unroll
        for (int c = 0; c < 8; ++c) {
            s16x8 b = *(const s16x8*)(W2t + ((size_t)(c * 16 + l16) << 7) + quad * 8 + k0);
            acc[c] = __builtin_amdgcn_mfma_f32_16x16x32_bf16(a, b, acc[c], 0, 0, 0);
        }
    }

    // ---- epilogue: residual + LN ----
    float b2v[8], gv[8], bbv[8];
#pragma unroll
    for (int c = 0; c < 8; ++c) {
        int col = c * 16 + l16;
        b2v[c] = B2[col];
        gv[c] = G[col];
        bbv[c] = Bb[col];
    }

#pragma unroll
    for (int reg = 0; reg < 4; ++reg) {
        int grow = r0 + quad * 4 + reg;
        bool rv = grow < N;
        float z[8];
        float s1 = 0.f, s2 = 0.f;
#pragma unroll
        for (int c = 0; c < 8; ++c) {
            float hv = rv ? bf2f(hb[((size_t)grow << 7) + c * 16 + l16]) : 0.f;
            z[c] = acc[c][reg] + b2v[c] + hv;
            s1 += z[c];
            s2 += z[c] * z[c];
        }
#pragma unroll
        for (int off = 1; off < 16; off <<= 1) {
            s1 += __shfl_xor(s1, off, 64);
            s2 += __shfl_xor(s2, off, 64);
        }
        float mean = s1 * (1.0f / 128.0f);
        float var = s2 * (1.0f / 128.0f) - mean * mean;
        float rs = rsqrtf(var + LN_EPS);
        if (rv) {
#pragma unroll
            for (int c = 0; c < 8; ++c) {
                int col = c * 16 + l16;
                float o = (z[c] - mean) * rs * gv[c] + bbv[c];
                hb[((size_t)grow << 7) + col] = f2bf(o);
                if (out_f32) out_f32[((size_t)grow << 7) + col] = o;
            }
        }
    }
}

// ---------------- launch ----------------

extern "C" void kernel_launch(void* const* d_in, const int* in_sizes, int n_in,
                              void* d_out, int out_size, void* d_ws, size_t ws_size,
                              hipStream_t stream) {
    const float* x    = (const float*)d_in[0];
    const int*   ei   = (const int*)d_in[1];
    const float* in_w = (const float*)d_in[2];
    const float* in_b = (const float*)d_in[3];
    const float* w1   = (const float*)d_in[4];
    const float* b1   = (const float*)d_in[5];
    const float* w2   = (const float*)d_in[6];
    const float* b2   = (const float*)d_in[7];
    const float* ln_g = (const float*)d_in[8];
    const float* ln_b = (const float*)d_in[9];

    const int N = in_sizes[0] / DIM;               // 50000
    const int E = in_sizes[1] / 2;                 // 640000
    const int LAYERS = in_sizes[4] / (DIM * DIM);  // 3

    const int* e_src = ei;
    const int* e_dst = ei + E;

    // workspace layout
    char* ws = (char*)d_ws;
    unsigned short* hb     = (unsigned short*)ws;  ws += (size_t)N * DIM * 2;
    unsigned short* m_bf   = (unsigned short*)ws;  ws += (size_t)N * DIM * 2;
    int*            counts = (int*)ws;             ws += (size_t)N * 4;
    int*            rowptr = (int*)ws;             ws += (size_t)(N + 1) * 4;
    int*            cursor = (int*)ws;             ws += (size_t)N * 4;
    float*          dinv   = (float*)ws;           ws += (size_t)N * 4;
    int*            srcidx = (int*)ws;             ws += (size_t)E * 4;
    int*            bsum   = (int*)ws;             ws += 4096;
    int*            bofs   = (int*)ws;             ws += 4096;
    unsigned short* wt     = (unsigned short*)ws;  ws += (size_t)(2 * LAYERS + 1) * DIM * DIM * 2;

    const int nScanBlocks = (N + 1023) / 1024;
    const int nMat = 2 * LAYERS + 1;

    // --- CSR build (deg is layer-invariant) + weight conversion ---
    hipMemsetAsync(counts, 0, (size_t)N * 4, stream);
    count_deg<<<(E + 255) / 256, 256, 0, stream>>>(e_dst, E, counts);
    scan_partials<<<nScanBlocks, 256, 0, stream>>>(counts, N, bsum);
    scan_bsums<<<1, 64, 0, stream>>>(bsum, bofs, nScanBlocks, rowptr, N, E);
    scan_final<<<nScanBlocks, 256, 0, stream>>>(counts, N, bofs, rowptr, cursor, dinv);
    fill_csr<<<(E + 255) / 256, 256, 0, stream>>>(e_src, e_dst, E, cursor, srcidx);
    cvt_weights<<<nMat * 8, 256, 0, stream>>>(in_w, w1, w2, wt, LAYERS);

    const unsigned short* in_wt = wt;
    const unsigned short* w1t   = wt + (size_t)DIM * DIM;
    const unsigned short* w2t   = wt + (size_t)(1 + LAYERS) * DIM * DIM;

    // --- input projection ---
    int gemm_grid = (N + 63) / 64;
    gemm_bias_mfma<<<gemm_grid, 256, 0, stream>>>(x, in_wt, in_b, hb, N);

    // --- layers ---
    for (int i = 0; i < LAYERS; ++i) {
        aggregate<<<(N + 15) / 16, 256, 0, stream>>>(hb, rowptr, srcidx, dinv, m_bf, N);
        float* out = (i == LAYERS - 1) ? (float*)d_out : nullptr;
        mlp_ln_mfma<<<gemm_grid, 256, 0, stream>>>(m_bf, hb,
                                                   w1t + (size_t)i * DIM * DIM, b1 + (size_t)i * DIM,
                                                   w2t + (size_t)i * DIM * DIM, b2 + (size_t)i * DIM,
                                                   ln_g + (size_t)i * DIM, ln_b + (size_t)i * DIM,
                                                   out, N);
    }
}

// Round 5
// 423.260 us; speedup vs baseline: 1.6169x; 1.0365x over previous
//
#include <hip/hip_runtime.h>

#define DIM 128
#define LN_EPS 1e-5f

typedef __attribute__((ext_vector_type(8))) short s16x8;   // 8 bf16 in 4 VGPRs
typedef __attribute__((ext_vector_type(4))) float f32x4;
typedef __attribute__((ext_vector_type(4))) unsigned int u32x4;

__device__ __forceinline__ unsigned short f2bf(float f) {
    unsigned u = __float_as_uint(f);
    unsigned r = u + 0x7fffu + ((u >> 16) & 1u);   // round-to-nearest-even
    return (unsigned short)(r >> 16);
}

// ---------------- CSR build ----------------

__global__ void count_deg(const int* __restrict__ dst, int E, int* __restrict__ counts) {
    int i = blockIdx.x * 256 + threadIdx.x;
    if (i < E) atomicAdd(&counts[dst[i]], 1);
}

__global__ __launch_bounds__(256) void scan_partials(const int* __restrict__ counts, int n,
                                                     int* __restrict__ bsum) {
    int base = blockIdx.x * 1024 + threadIdx.x * 4;
    int s = 0;
#pragma unroll
    for (int j = 0; j < 4; ++j) {
        int i = base + j;
        if (i < n) s += counts[i];
    }
#pragma unroll
    for (int off = 32; off > 0; off >>= 1) s += __shfl_xor(s, off, 64);
    __shared__ int wsum[4];
    int lane = threadIdx.x & 63, wid = threadIdx.x >> 6;
    if (lane == 0) wsum[wid] = s;
    __syncthreads();
    if (threadIdx.x == 0) bsum[blockIdx.x] = wsum[0] + wsum[1] + wsum[2] + wsum[3];
}

__global__ __launch_bounds__(64) void scan_bsums(const int* __restrict__ bsum,
                                                 int* __restrict__ bofs, int nb,
                                                 int* __restrict__ rowptr, int N, int E) {
    int lane = threadIdx.x;
    int carry = 0;
    for (int base = 0; base < nb; base += 64) {
        int v = (base + lane < nb) ? bsum[base + lane] : 0;
        int incl = v;
#pragma unroll
        for (int off = 1; off < 64; off <<= 1) {
            int t = __shfl_up(incl, off, 64);
            if (lane >= off) incl += t;
        }
        if (base + lane < nb) bofs[base + lane] = carry + incl - v;
        carry += __shfl(incl, 63, 64);
    }
    if (lane == 0) rowptr[N] = E;
}

__global__ __launch_bounds__(256) void scan_final(const int* __restrict__ counts, int n,
                                                  const int* __restrict__ bofs,
                                                  int* __restrict__ rowptr,
                                                  int* __restrict__ cursor,
                                                  float* __restrict__ dinv) {
    int base = blockIdx.x * 1024 + threadIdx.x * 4;
    int v[4];
#pragma unroll
    for (int j = 0; j < 4; ++j) {
        int i = base + j;
        v[j] = (i < n) ? counts[i] : 0;
    }
    int tsum = v[0] + v[1] + v[2] + v[3];
    int lane = threadIdx.x & 63, wid = threadIdx.x >> 6;
    int incl = tsum;
#pragma unroll
    for (int off = 1; off < 64; off <<= 1) {
        int t = __shfl_up(incl, off, 64);
        if (lane >= off) incl += t;
    }
    __shared__ int wsum[4];
    if (lane == 63) wsum[wid] = incl;
    __syncthreads();
    int wofs = 0;
    for (int w = 0; w < 4; ++w)
        if (w < wid) wofs += wsum[w];
    int excl = bofs[blockIdx.x] + wofs + (incl - tsum);
#pragma unroll
    for (int j = 0; j < 4; ++j) {
        int i = base + j;
        if (i < n) {
            rowptr[i] = excl;
            cursor[i] = excl;
            dinv[i] = 1.0f / (float)((v[j] > 1) ? v[j] : 1);
            excl += v[j];
        }
    }
}

__global__ void fill_csr(const int* __restrict__ src, const int* __restrict__ dst, int E,
                         int* __restrict__ cursor, int* __restrict__ srcidx) {
    int i = blockIdx.x * 256 + threadIdx.x;
    if (i < E) {
        int p = atomicAdd(&cursor[dst[i]], 1);
        srcidx[p] = src[i];
    }
}

// ---------------- weight conversion: f32 row-major -> bf16 transposed ----------------

__global__ __launch_bounds__(256) void cvt_weights(const float* __restrict__ in_w,
                                                   const float* __restrict__ w1,
                                                   const float* __restrict__ w2,
                                                   unsigned short* __restrict__ wt, int L) {
    int mat = blockIdx.x >> 3, part = blockIdx.x & 7;
    const float* src;
    if (mat == 0) src = in_w;
    else if (mat <= L) src = w1 + (size_t)(mat - 1) * DIM * DIM;
    else src = w2 + (size_t)(mat - 1 - L) * DIM * DIM;
    unsigned short* dst = wt + (size_t)mat * DIM * DIM;
    int base = part * 2048 + threadIdx.x;
#pragma unroll
    for (int j = 0; j < 8; ++j) {
        int i = base + j * 256;
        int k = i >> 7, n = i & 127;
        dst[n * DIM + k] = f2bf(src[i]);
    }
}

// ---------------- input projection (MFMA): hb = bf16(x @ in_w + in_b) ----------------

__global__ __launch_bounds__(256) void gemm_bias_mfma(const float* __restrict__ x,
                                                      const unsigned short* __restrict__ Wt,
                                                      const float* __restrict__ bias,
                                                      unsigned short* __restrict__ hb, int N) {
    int tid = threadIdx.x;
    int wv = tid >> 6, lane = tid & 63;
    int quad = lane >> 4, l16 = lane & 15;
    int r0 = blockIdx.x * 64 + wv * 16;
    int arow = r0 + l16;
    bool avalid = arow < N;

    f32x4 acc[8];
#pragma unroll
    for (int c = 0; c < 8; ++c) acc[c] = (f32x4){0.f, 0.f, 0.f, 0.f};

    const float4* xp = (const float4*)(x + (size_t)arow * DIM) + quad * 2;
#pragma unroll
    for (int k0 = 0; k0 < 128; k0 += 32) {
        s16x8 a = {0, 0, 0, 0, 0, 0, 0, 0};
        if (avalid) {
            float4 f0 = xp[k0 / 4];
            float4 f1 = xp[k0 / 4 + 1];
            a[0] = (short)f2bf(f0.x); a[1] = (short)f2bf(f0.y);
            a[2] = (short)f2bf(f0.z); a[3] = (short)f2bf(f0.w);
            a[4] = (short)f2bf(f1.x); a[5] = (short)f2bf(f1.y);
            a[6] = (short)f2bf(f1.z); a[7] = (short)f2bf(f1.w);
        }
        s16x8 b[8];
#pragma unroll
        for (int c = 0; c < 8; ++c)
            b[c] = *(const s16x8*)(Wt + ((size_t)(c * 16 + l16) << 7) + quad * 8 + k0);
#pragma unroll
        for (int c = 0; c < 8; ++c)
            acc[c] = __builtin_amdgcn_mfma_f32_16x16x32_bf16(a, b[c], acc[c], 0, 0, 0);
    }

#pragma unroll
    for (int reg = 0; reg < 4; ++reg) {
        int grow = r0 + quad * 4 + reg;
        if (grow < N) {
#pragma unroll
            for (int c = 0; c < 8; ++c) {
                int col = c * 16 + l16;
                hb[((size_t)grow << 7) + col] = f2bf(acc[c][reg] + bias[col]);
            }
        }
    }
}

// ---------------- fused layer: gather + MLP + residual + LN ----------------
// hout = bf16(LN(hin + relu((gather(hin)/deg)@W1+b1)@W2+b2)), optional f32 out.
// Barrier-free: each wave owns LDS rows [wv*16, wv*16+16) for m-tile, A-frags, and P.

__global__ __launch_bounds__(256) void agg_mlp_ln(const unsigned short* __restrict__ hin,
                                                  const int* __restrict__ rowptr,
                                                  const int* __restrict__ srcidx,
                                                  const float* __restrict__ dinv,
                                                  const unsigned short* __restrict__ W1t,
                                                  const float* __restrict__ B1,
                                                  const unsigned short* __restrict__ W2t,
                                                  const float* __restrict__ B2,
                                                  const float* __restrict__ G,
                                                  const float* __restrict__ Bb,
                                                  unsigned short* __restrict__ hout,
                                                  float* __restrict__ out_f32, int N) {
    __shared__ unsigned short M[64][136];   // +8 pad
    int tid = threadIdx.x;
    int wv = tid >> 6, lane = tid & 63;
    int quad = lane >> 4, l16 = lane & 15;
    int r0 = blockIdx.x * 64;
    int rowbase = r0 + wv * 16;

    // ---- gather: quad handles 4 nodes, cursors interleaved + 2-deep unroll (8 loads in flight)
    int n0 = rowbase + quad * 4;
    float ac[4][8];
#pragma unroll
    for (int i = 0; i < 4; ++i)
#pragma unroll
        for (int j = 0; j < 8; ++j) ac[i][j] = 0.f;

    int ec[4], ee[4];
#pragma unroll
    for (int i = 0; i < 4; ++i) {
        int nd = n0 + i;
        bool v = nd < N;
        ec[i] = v ? rowptr[nd] : 0;
        ee[i] = v ? rowptr[nd + 1] : 0;
    }

    while (ec[0] < ee[0] || ec[1] < ee[1] || ec[2] < ee[2] || ec[3] < ee[3]) {
        u32x4 v0[4], v1[4];
        bool p0[4], p1[4];
#pragma unroll
        for (int i = 0; i < 4; ++i) {
            p0[i] = ec[i] < ee[i];
            p1[i] = ec[i] + 1 < ee[i];
        }
#pragma unroll
        for (int i = 0; i < 4; ++i)
            if (p0[i]) v0[i] = *(const u32x4*)(hin + ((size_t)srcidx[ec[i]] << 7) + l16 * 8);
#pragma unroll
        for (int i = 0; i < 4; ++i)
            if (p1[i]) v1[i] = *(const u32x4*)(hin + ((size_t)srcidx[ec[i] + 1] << 7) + l16 * 8);
#pragma unroll
        for (int i = 0; i < 4; ++i) {
            if (p0[i]) {
#pragma unroll
                for (int j = 0; j < 4; ++j) {
                    ac[i][2 * j]     += __uint_as_float(v0[i][j] << 16);
                    ac[i][2 * j + 1] += __uint_as_float(v0[i][j] & 0xffff0000u);
                }
            }
            if (p1[i]) {
#pragma unroll
                for (int j = 0; j < 4; ++j) {
                    ac[i][2 * j]     += __uint_as_float(v1[i][j] << 16);
                    ac[i][2 * j + 1] += __uint_as_float(v1[i][j] & 0xffff0000u);
                }
            }
            ec[i] += 2;
        }
    }

    // scale by 1/deg, write m-tile rows (wave-own) to LDS
#pragma unroll
    for (int i = 0; i < 4; ++i) {
        int nd = n0 + i;
        float di = (nd < N) ? dinv[nd] : 0.f;
        u32x4 o;
#pragma unroll
        for (int j = 0; j < 4; ++j) {
            unsigned lo = f2bf(ac[i][2 * j] * di);
            unsigned hi = f2bf(ac[i][2 * j + 1] * di);
            o[j] = lo | (hi << 16);
        }
        *(u32x4*)(&M[wv * 16 + quad * 4 + i][l16 * 8]) = o;
    }

    // ---- GEMM1: relu(m @ W1 + b1) -> P (same LDS rows)
    f32x4 acc[8];
#pragma unroll
    for (int c = 0; c < 8; ++c) acc[c] = (f32x4){0.f, 0.f, 0.f, 0.f};

#pragma unroll
    for (int k0 = 0; k0 < 128; k0 += 32) {
        s16x8 a = *(const s16x8*)(&M[wv * 16 + l16][quad * 8 + k0]);
        s16x8 b[8];
#pragma unroll
        for (int c = 0; c < 8; ++c)
            b[c] = *(const s16x8*)(W1t + ((size_t)(c * 16 + l16) << 7) + quad * 8 + k0);
#pragma unroll
        for (int c = 0; c < 8; ++c)
            acc[c] = __builtin_amdgcn_mfma_f32_16x16x32_bf16(a, b[c], acc[c], 0, 0, 0);
    }

#pragma unroll
    for (int c = 0; c < 8; ++c) {
        float bv = B1[c * 16 + l16];
#pragma unroll
        for (int reg = 0; reg < 4; ++reg) {
            float v = fmaxf(acc[c][reg] + bv, 0.f);
            M[wv * 16 + quad * 4 + reg][c * 16 + l16] = f2bf(v);
        }
    }

    // ---- GEMM2: P @ W2
#pragma unroll
    for (int c = 0; c < 8; ++c) acc[c] = (f32x4){0.f, 0.f, 0.f, 0.f};

#pragma unroll
    for (int k0 = 0; k0 < 128; k0 += 32) {
        s16x8 a = *(const s16x8*)(&M[wv * 16 + l16][quad * 8 + k0]);
        s16x8 b[8];
#pragma unroll
        for (int c = 0; c < 8; ++c)
            b[c] = *(const s16x8*)(W2t + ((size_t)(c * 16 + l16) << 7) + quad * 8 + k0);
#pragma unroll
        for (int c = 0; c < 8; ++c)
            acc[c] = __builtin_amdgcn_mfma_f32_16x16x32_bf16(a, b[c], acc[c], 0, 0, 0);
    }

    // ---- epilogue: residual (from hin) + LN -> hout (+ f32 out on last layer)
    float b2v[8], gv[8], bbv[8];
#pragma unroll
    for (int c = 0; c < 8; ++c) {
        int col = c * 16 + l16;
        b2v[c] = B2[col];
        gv[c] = G[col];
        bbv[c] = Bb[col];
    }

#pragma unroll
    for (int reg = 0; reg < 4; ++reg) {
        int grow = rowbase + quad * 4 + reg;
        bool rv = grow < N;
        float z[8];
        float s1 = 0.f, s2 = 0.f;
#pragma unroll
        for (int c = 0; c < 8; ++c) {
            float hv = 0.f;
            if (rv) {
                unsigned short u = hin[((size_t)grow << 7) + c * 16 + l16];
                hv = __uint_as_float(((unsigned)u) << 16);
            }
            z[c] = acc[c][reg] + b2v[c] + hv;
            s1 += z[c];
            s2 += z[c] * z[c];
        }
#pragma unroll
        for (int off = 1; off < 16; off <<= 1) {
            s1 += __shfl_xor(s1, off, 64);
            s2 += __shfl_xor(s2, off, 64);
        }
        float mean = s1 * (1.0f / 128.0f);
        float var = s2 * (1.0f / 128.0f) - mean * mean;
        float rs = rsqrtf(var + LN_EPS);
        if (rv) {
#pragma unroll
            for (int c = 0; c < 8; ++c) {
                int col = c * 16 + l16;
                float o = (z[c] - mean) * rs * gv[c] + bbv[c];
                hout[((size_t)grow << 7) + col] = f2bf(o);
                if (out_f32) out_f32[((size_t)grow << 7) + col] = o;
            }
        }
    }
}

// ---------------- launch ----------------

extern "C" void kernel_launch(void* const* d_in, const int* in_sizes, int n_in,
                              void* d_out, int out_size, void* d_ws, size_t ws_size,
                              hipStream_t stream) {
    const float* x    = (const float*)d_in[0];
    const int*   ei   = (const int*)d_in[1];
    const float* in_w = (const float*)d_in[2];
    const float* in_b = (const float*)d_in[3];
    const float* w1   = (const float*)d_in[4];
    const float* b1   = (const float*)d_in[5];
    const float* w2   = (const float*)d_in[6];
    const float* b2   = (const float*)d_in[7];
    const float* ln_g = (const float*)d_in[8];
    const float* ln_b = (const float*)d_in[9];

    const int N = in_sizes[0] / DIM;               // 50000
    const int E = in_sizes[1] / 2;                 // 640000
    const int LAYERS = in_sizes[4] / (DIM * DIM);  // 3

    const int* e_src = ei;
    const int* e_dst = ei + E;

    // workspace layout
    char* ws = (char*)d_ws;
    unsigned short* hb0    = (unsigned short*)ws;  ws += (size_t)N * DIM * 2;
    unsigned short* hb1    = (unsigned short*)ws;  ws += (size_t)N * DIM * 2;
    int*            counts = (int*)ws;             ws += (size_t)N * 4;
    int*            rowptr = (int*)ws;             ws += (size_t)(N + 1) * 4;
    int*            cursor = (int*)ws;             ws += (size_t)N * 4;
    float*          dinv   = (float*)ws;           ws += (size_t)N * 4;
    int*            srcidx = (int*)ws;             ws += (size_t)E * 4;
    int*            bsum   = (int*)ws;             ws += 4096;
    int*            bofs   = (int*)ws;             ws += 4096;
    unsigned short* wt     = (unsigned short*)ws;  ws += (size_t)(2 * LAYERS + 1) * DIM * DIM * 2;

    const int nScanBlocks = (N + 1023) / 1024;
    const int nMat = 2 * LAYERS + 1;

    // --- CSR build (deg is layer-invariant) + weight conversion ---
    hipMemsetAsync(counts, 0, (size_t)N * 4, stream);
    count_deg<<<(E + 255) / 256, 256, 0, stream>>>(e_dst, E, counts);
    scan_partials<<<nScanBlocks, 256, 0, stream>>>(counts, N, bsum);
    scan_bsums<<<1, 64, 0, stream>>>(bsum, bofs, nScanBlocks, rowptr, N, E);
    scan_final<<<nScanBlocks, 256, 0, stream>>>(counts, N, bofs, rowptr, cursor, dinv);
    fill_csr<<<(E + 255) / 256, 256, 0, stream>>>(e_src, e_dst, E, cursor, srcidx);
    cvt_weights<<<nMat * 8, 256, 0, stream>>>(in_w, w1, w2, wt, LAYERS);

    const unsigned short* in_wt = wt;
    const unsigned short* w1t   = wt + (size_t)DIM * DIM;
    const unsigned short* w2t   = wt + (size_t)(1 + LAYERS) * DIM * DIM;

    // --- input projection ---
    int gemm_grid = (N + 63) / 64;
    gemm_bias_mfma<<<gemm_grid, 256, 0, stream>>>(x, in_wt, in_b, hb0, N);

    // --- layers (h ping-pong; gather must read pre-update h) ---
    unsigned short* hin = hb0;
    unsigned short* hout = hb1;
    for (int i = 0; i < LAYERS; ++i) {
        float* out = (i == LAYERS - 1) ? (float*)d_out : nullptr;
        agg_mlp_ln<<<gemm_grid, 256, 0, stream>>>(hin, rowptr, srcidx, dinv,
                                                  w1t + (size_t)i * DIM * DIM, b1 + (size_t)i * DIM,
                                                  w2t + (size_t)i * DIM * DIM, b2 + (size_t)i * DIM,
                                                  ln_g + (size_t)i * DIM, ln_b + (size_t)i * DIM,
                                                  hout, out, N);
        unsigned short* t = hin; hin = hout; hout = t;
    }
}

// Round 6
// 369.367 us; speedup vs baseline: 1.8528x; 1.1459x over previous
//
#include <hip/hip_runtime.h>

#define DIM 128
#define LN_EPS 1e-5f

typedef __attribute__((ext_vector_type(8))) short s16x8;   // 8 bf16 in 4 VGPRs
typedef __attribute__((ext_vector_type(4))) float f32x4;
typedef __attribute__((ext_vector_type(4))) unsigned int u32x4;

__device__ __forceinline__ unsigned short f2bf(float f) {
    unsigned u = __float_as_uint(f);
    unsigned r = u + 0x7fffu + ((u >> 16) & 1u);   // round-to-nearest-even
    return (unsigned short)(r >> 16);
}
__device__ __forceinline__ float bf2f(unsigned short b) {
    return __uint_as_float(((unsigned)b) << 16);
}

// ---------------- CSR build ----------------

__global__ void count_deg(const int* __restrict__ dst, int E, int* __restrict__ counts) {
    int i = blockIdx.x * 256 + threadIdx.x;
    if (i < E) atomicAdd(&counts[dst[i]], 1);
}

__global__ __launch_bounds__(256) void scan_partials(const int* __restrict__ counts, int n,
                                                     int* __restrict__ bsum) {
    int base = blockIdx.x * 1024 + threadIdx.x * 4;
    int s = 0;
#pragma unroll
    for (int j = 0; j < 4; ++j) {
        int i = base + j;
        if (i < n) s += counts[i];
    }
#pragma unroll
    for (int off = 32; off > 0; off >>= 1) s += __shfl_xor(s, off, 64);
    __shared__ int wsum[4];
    int lane = threadIdx.x & 63, wid = threadIdx.x >> 6;
    if (lane == 0) wsum[wid] = s;
    __syncthreads();
    if (threadIdx.x == 0) bsum[blockIdx.x] = wsum[0] + wsum[1] + wsum[2] + wsum[3];
}

__global__ __launch_bounds__(64) void scan_bsums(const int* __restrict__ bsum,
                                                 int* __restrict__ bofs, int nb,
                                                 int* __restrict__ rowptr, int N, int E) {
    int lane = threadIdx.x;
    int carry = 0;
    for (int base = 0; base < nb; base += 64) {
        int v = (base + lane < nb) ? bsum[base + lane] : 0;
        int incl = v;
#pragma unroll
        for (int off = 1; off < 64; off <<= 1) {
            int t = __shfl_up(incl, off, 64);
            if (lane >= off) incl += t;
        }
        if (base + lane < nb) bofs[base + lane] = carry + incl - v;
        carry += __shfl(incl, 63, 64);
    }
    if (lane == 0) rowptr[N] = E;
}

__global__ __launch_bounds__(256) void scan_final(const int* __restrict__ counts, int n,
                                                  const int* __restrict__ bofs,
                                                  int* __restrict__ rowptr,
                                                  int* __restrict__ cursor,
                                                  float* __restrict__ dinv) {
    int base = blockIdx.x * 1024 + threadIdx.x * 4;
    int v[4];
#pragma unroll
    for (int j = 0; j < 4; ++j) {
        int i = base + j;
        v[j] = (i < n) ? counts[i] : 0;
    }
    int tsum = v[0] + v[1] + v[2] + v[3];
    int lane = threadIdx.x & 63, wid = threadIdx.x >> 6;
    int incl = tsum;
#pragma unroll
    for (int off = 1; off < 64; off <<= 1) {
        int t = __shfl_up(incl, off, 64);
        if (lane >= off) incl += t;
    }
    __shared__ int wsum[4];
    if (lane == 63) wsum[wid] = incl;
    __syncthreads();
    int wofs = 0;
    for (int w = 0; w < 4; ++w)
        if (w < wid) wofs += wsum[w];
    int excl = bofs[blockIdx.x] + wofs + (incl - tsum);
#pragma unroll
    for (int j = 0; j < 4; ++j) {
        int i = base + j;
        if (i < n) {
            rowptr[i] = excl;
            cursor[i] = excl;
            dinv[i] = 1.0f / (float)((v[j] > 1) ? v[j] : 1);
            excl += v[j];
        }
    }
}

__global__ void fill_csr(const int* __restrict__ src, const int* __restrict__ dst, int E,
                         int* __restrict__ cursor, int* __restrict__ srcidx) {
    int i = blockIdx.x * 256 + threadIdx.x;
    if (i < E) {
        int p = atomicAdd(&cursor[dst[i]], 1);
        srcidx[p] = src[i];
    }
}

// ---------------- weight conversion: f32 row-major -> bf16 transposed ----------------

__global__ __launch_bounds__(256) void cvt_weights(const float* __restrict__ in_w,
                                                   const float* __restrict__ w1,
                                                   const float* __restrict__ w2,
                                                   unsigned short* __restrict__ wt, int L) {
    int mat = blockIdx.x >> 3, part = blockIdx.x & 7;
    const float* src;
    if (mat == 0) src = in_w;
    else if (mat <= L) src = w1 + (size_t)(mat - 1) * DIM * DIM;
    else src = w2 + (size_t)(mat - 1 - L) * DIM * DIM;
    unsigned short* dst = wt + (size_t)mat * DIM * DIM;
    int base = part * 2048 + threadIdx.x;
#pragma unroll
    for (int j = 0; j < 8; ++j) {
        int i = base + j * 256;
        int k = i >> 7, n = i & 127;
        dst[n * DIM + k] = f2bf(src[i]);
    }
}

// ---------------- input projection (MFMA, col-split): hb = bf16(x @ in_w + in_b) ----
// block = 16 rows, 4 waves; wave s computes cols [s*32, s*32+32). No LDS, no barrier.

__global__ __launch_bounds__(256) void gemm_bias_mfma(const float* __restrict__ x,
                                                      const unsigned short* __restrict__ Wt,
                                                      const float* __restrict__ bias,
                                                      unsigned short* __restrict__ hb, int N) {
    int tid = threadIdx.x;
    int s = tid >> 6, lane = tid & 63;
    int quad = lane >> 4, l16 = lane & 15;
    int r0 = blockIdx.x * 16;
    int cs = s * 32;
    int arow = r0 + l16;
    bool av = arow < N;

    f32x4 acc[2];
    acc[0] = (f32x4){0.f, 0.f, 0.f, 0.f};
    acc[1] = (f32x4){0.f, 0.f, 0.f, 0.f};

    const float4* xp = (const float4*)(x + ((size_t)(av ? arow : 0) << 7)) + quad * 2;
#pragma unroll
    for (int k0 = 0; k0 < 128; k0 += 32) {
        s16x8 a = {0, 0, 0, 0, 0, 0, 0, 0};
        if (av) {
            float4 f0 = xp[k0 / 4];
            float4 f1 = xp[k0 / 4 + 1];
            a[0] = (short)f2bf(f0.x); a[1] = (short)f2bf(f0.y);
            a[2] = (short)f2bf(f0.z); a[3] = (short)f2bf(f0.w);
            a[4] = (short)f2bf(f1.x); a[5] = (short)f2bf(f1.y);
            a[6] = (short)f2bf(f1.z); a[7] = (short)f2bf(f1.w);
        }
        s16x8 b0 = *(const s16x8*)(Wt + ((size_t)(cs + l16) << 7) + quad * 8 + k0);
        s16x8 b1 = *(const s16x8*)(Wt + ((size_t)(cs + 16 + l16) << 7) + quad * 8 + k0);
        acc[0] = __builtin_amdgcn_mfma_f32_16x16x32_bf16(a, b0, acc[0], 0, 0, 0);
        acc[1] = __builtin_amdgcn_mfma_f32_16x16x32_bf16(a, b1, acc[1], 0, 0, 0);
    }

#pragma unroll
    for (int c = 0; c < 2; ++c) {
        int col = cs + c * 16 + l16;
        float bv = bias[col];
#pragma unroll
        for (int reg = 0; reg < 4; ++reg) {
            int grow = r0 + quad * 4 + reg;
            if (grow < N) hb[((size_t)grow << 7) + col] = f2bf(acc[c][reg] + bv);
        }
    }
}

// ---------------- fused layer (col-split): gather + MLP + residual + LN ----------------
// block = 16 rows, 4 waves; wave s owns col-slice [s*32, s*32+32) for gather, B-frags,
// P-cols, and output. A-frags shared via LDS (3 barriers).

__global__ __launch_bounds__(256) void agg_mlp_ln(const unsigned short* __restrict__ hin,
                                                  const int* __restrict__ rowptr,
                                                  const int* __restrict__ srcidx,
                                                  const float* __restrict__ dinv,
                                                  const unsigned short* __restrict__ W1t,
                                                  const float* __restrict__ B1,
                                                  const unsigned short* __restrict__ W2t,
                                                  const float* __restrict__ B2,
                                                  const float* __restrict__ G,
                                                  const float* __restrict__ Bb,
                                                  unsigned short* __restrict__ hout,
                                                  float* __restrict__ out_f32, int N) {
    __shared__ unsigned short M[16][132];   // +4 pad: conflict-free b128 A-frag reads
    __shared__ unsigned short P[16][132];
    __shared__ float s1p[4][16], s2p[4][16];

    int tid = threadIdx.x;
    int s = tid >> 6, lane = tid & 63;
    int quad = lane >> 4, l16 = lane & 15;
    int g = lane >> 2, li = lane & 3;       // gather: group g owns node r0+g
    int r0 = blockIdx.x * 16;
    int cs = s * 32;

    // ---- gather: 16 nodes/block; lane li covers 16B of wave's 32-col slice ----
    int nd = r0 + g;
    bool nv = nd < N;
    int e  = nv ? rowptr[nd] : 0;
    int ee = nv ? rowptr[nd + 1] : 0;

    float a0[8] = {0, 0, 0, 0, 0, 0, 0, 0};
    float a1[8] = {0, 0, 0, 0, 0, 0, 0, 0};
    const unsigned short* hsl = hin + cs + li * 8;

    while (__any(e < ee)) {
        // coalesced srcidx fetch: lane li reads e+li, broadcast to group
        int myidx = (e + li < ee) ? srcidx[e + li] : 0;
        int i0 = __shfl(myidx, (g << 2) | 0, 64);
        int i1 = __shfl(myidx, (g << 2) | 1, 64);
        int i2 = __shfl(myidx, (g << 2) | 2, 64);
        int i3 = __shfl(myidx, (g << 2) | 3, 64);
        bool p0 = e < ee, p1 = e + 1 < ee, p2 = e + 2 < ee, p3 = e + 3 < ee;
        u32x4 v0, v1, v2, v3;
        if (p0) v0 = *(const u32x4*)(hsl + ((size_t)i0 << 7));
        if (p1) v1 = *(const u32x4*)(hsl + ((size_t)i1 << 7));
        if (p2) v2 = *(const u32x4*)(hsl + ((size_t)i2 << 7));
        if (p3) v3 = *(const u32x4*)(hsl + ((size_t)i3 << 7));
        if (p0) {
#pragma unroll
            for (int j = 0; j < 4; ++j) {
                a0[2 * j]     += __uint_as_float(v0[j] << 16);
                a0[2 * j + 1] += __uint_as_float(v0[j] & 0xffff0000u);
            }
        }
        if (p1) {
#pragma unroll
            for (int j = 0; j < 4; ++j) {
                a1[2 * j]     += __uint_as_float(v1[j] << 16);
                a1[2 * j + 1] += __uint_as_float(v1[j] & 0xffff0000u);
            }
        }
        if (p2) {
#pragma unroll
            for (int j = 0; j < 4; ++j) {
                a0[2 * j]     += __uint_as_float(v2[j] << 16);
                a0[2 * j + 1] += __uint_as_float(v2[j] & 0xffff0000u);
            }
        }
        if (p3) {
#pragma unroll
            for (int j = 0; j < 4; ++j) {
                a1[2 * j]     += __uint_as_float(v3[j] << 16);
                a1[2 * j + 1] += __uint_as_float(v3[j] & 0xffff0000u);
            }
        }
        e += 4;
    }

    {
        float di = nv ? dinv[nd] : 0.f;
        u32x4 o;
#pragma unroll
        for (int j = 0; j < 4; ++j) {
            unsigned lo = f2bf((a0[2 * j] + a1[2 * j]) * di);
            unsigned hi = f2bf((a0[2 * j + 1] + a1[2 * j + 1]) * di);
            o[j] = lo | (hi << 16);
        }
        *(u32x4*)(&M[g][cs + li * 8]) = o;
    }
    __syncthreads();

    // ---- GEMM1: relu(m @ W1 + b1); wave computes 16 rows x 32 cols ----
    f32x4 acc[2];
    acc[0] = (f32x4){0.f, 0.f, 0.f, 0.f};
    acc[1] = (f32x4){0.f, 0.f, 0.f, 0.f};
#pragma unroll
    for (int k0 = 0; k0 < 128; k0 += 32) {
        s16x8 a = *(const s16x8*)(&M[l16][quad * 8 + k0]);
        s16x8 b0 = *(const s16x8*)(W1t + ((size_t)(cs + l16) << 7) + quad * 8 + k0);
        s16x8 b1 = *(const s16x8*)(W1t + ((size_t)(cs + 16 + l16) << 7) + quad * 8 + k0);
        acc[0] = __builtin_amdgcn_mfma_f32_16x16x32_bf16(a, b0, acc[0], 0, 0, 0);
        acc[1] = __builtin_amdgcn_mfma_f32_16x16x32_bf16(a, b1, acc[1], 0, 0, 0);
    }
#pragma unroll
    for (int c = 0; c < 2; ++c) {
        int col = cs + c * 16 + l16;
        float bv = B1[col];
#pragma unroll
        for (int reg = 0; reg < 4; ++reg) {
            float v = fmaxf(acc[c][reg] + bv, 0.f);
            P[quad * 4 + reg][col] = f2bf(v);
        }
    }
    __syncthreads();

    // ---- GEMM2: P @ W2 ----
    acc[0] = (f32x4){0.f, 0.f, 0.f, 0.f};
    acc[1] = (f32x4){0.f, 0.f, 0.f, 0.f};
#pragma unroll
    for (int k0 = 0; k0 < 128; k0 += 32) {
        s16x8 a = *(const s16x8*)(&P[l16][quad * 8 + k0]);
        s16x8 b0 = *(const s16x8*)(W2t + ((size_t)(cs + l16) << 7) + quad * 8 + k0);
        s16x8 b1 = *(const s16x8*)(W2t + ((size_t)(cs + 16 + l16) << 7) + quad * 8 + k0);
        acc[0] = __builtin_amdgcn_mfma_f32_16x16x32_bf16(a, b0, acc[0], 0, 0, 0);
        acc[1] = __builtin_amdgcn_mfma_f32_16x16x32_bf16(a, b1, acc[1], 0, 0, 0);
    }

    // ---- epilogue: residual + LN (cross-wave row sums via LDS partials) ----
    float z[2][4];
    float ps1[4] = {0, 0, 0, 0}, ps2[4] = {0, 0, 0, 0};
#pragma unroll
    for (int c = 0; c < 2; ++c) {
        int col = cs + c * 16 + l16;
        float b2v = B2[col];
#pragma unroll
        for (int reg = 0; reg < 4; ++reg) {
            int grow = r0 + quad * 4 + reg;
            float hv = (grow < N) ? bf2f(hin[((size_t)grow << 7) + col]) : 0.f;
            float zz = acc[c][reg] + b2v + hv;
            z[c][reg] = zz;
            ps1[reg] += zz;
            ps2[reg] += zz * zz;
        }
    }
#pragma unroll
    for (int off = 1; off < 16; off <<= 1) {
#pragma unroll
        for (int reg = 0; reg < 4; ++reg) {
            ps1[reg] += __shfl_xor(ps1[reg], off, 64);
            ps2[reg] += __shfl_xor(ps2[reg], off, 64);
        }
    }
    if (l16 == 0) {
#pragma unroll
        for (int reg = 0; reg < 4; ++reg) {
            s1p[s][quad * 4 + reg] = ps1[reg];
            s2p[s][quad * 4 + reg] = ps2[reg];
        }
    }
    __syncthreads();

#pragma unroll
    for (int reg = 0; reg < 4; ++reg) {
        int row = quad * 4 + reg;
        float S1 = s1p[0][row] + s1p[1][row] + s1p[2][row] + s1p[3][row];
        float S2 = s2p[0][row] + s2p[1][row] + s2p[2][row] + s2p[3][row];
        float mean = S1 * (1.0f / 128.0f);
        float var = S2 * (1.0f / 128.0f) - mean * mean;
        float rs = rsqrtf(var + LN_EPS);
        int grow = r0 + row;
        if (grow < N) {
#pragma unroll
            for (int c = 0; c < 2; ++c) {
                int col = cs + c * 16 + l16;
                float o = (z[c][reg] - mean) * rs * G[col] + Bb[col];
                hout[((size_t)grow << 7) + col] = f2bf(o);
                if (out_f32) out_f32[((size_t)grow << 7) + col] = o;
            }
        }
    }
}

// ---------------- launch ----------------

extern "C" void kernel_launch(void* const* d_in, const int* in_sizes, int n_in,
                              void* d_out, int out_size, void* d_ws, size_t ws_size,
                              hipStream_t stream) {
    const float* x    = (const float*)d_in[0];
    const int*   ei   = (const int*)d_in[1];
    const float* in_w = (const float*)d_in[2];
    const float* in_b = (const float*)d_in[3];
    const float* w1   = (const float*)d_in[4];
    const float* b1   = (const float*)d_in[5];
    const float* w2   = (const float*)d_in[6];
    const float* b2   = (const float*)d_in[7];
    const float* ln_g = (const float*)d_in[8];
    const float* ln_b = (const float*)d_in[9];

    const int N = in_sizes[0] / DIM;               // 50000
    const int E = in_sizes[1] / 2;                 // 640000
    const int LAYERS = in_sizes[4] / (DIM * DIM);  // 3

    const int* e_src = ei;
    const int* e_dst = ei + E;

    // workspace layout
    char* ws = (char*)d_ws;
    unsigned short* hb0    = (unsigned short*)ws;  ws += (size_t)N * DIM * 2;
    unsigned short* hb1    = (unsigned short*)ws;  ws += (size_t)N * DIM * 2;
    int*            counts = (int*)ws;             ws += (size_t)N * 4;
    int*            rowptr = (int*)ws;             ws += (size_t)(N + 1) * 4;
    int*            cursor = (int*)ws;             ws += (size_t)N * 4;
    float*          dinv   = (float*)ws;           ws += (size_t)N * 4;
    int*            srcidx = (int*)ws;             ws += (size_t)E * 4;
    int*            bsum   = (int*)ws;             ws += 4096;
    int*            bofs   = (int*)ws;             ws += 4096;
    unsigned short* wt     = (unsigned short*)ws;  ws += (size_t)(2 * LAYERS + 1) * DIM * DIM * 2;

    const int nScanBlocks = (N + 1023) / 1024;
    const int nMat = 2 * LAYERS + 1;

    // --- CSR build (deg is layer-invariant) + weight conversion ---
    hipMemsetAsync(counts, 0, (size_t)N * 4, stream);
    count_deg<<<(E + 255) / 256, 256, 0, stream>>>(e_dst, E, counts);
    scan_partials<<<nScanBlocks, 256, 0, stream>>>(counts, N, bsum);
    scan_bsums<<<1, 64, 0, stream>>>(bsum, bofs, nScanBlocks, rowptr, N, E);
    scan_final<<<nScanBlocks, 256, 0, stream>>>(counts, N, bofs, rowptr, cursor, dinv);
    fill_csr<<<(E + 255) / 256, 256, 0, stream>>>(e_src, e_dst, E, cursor, srcidx);
    cvt_weights<<<nMat * 8, 256, 0, stream>>>(in_w, w1, w2, wt, LAYERS);

    const unsigned short* in_wt = wt;
    const unsigned short* w1t   = wt + (size_t)DIM * DIM;
    const unsigned short* w2t   = wt + (size_t)(1 + LAYERS) * DIM * DIM;

    // --- input projection ---
    int tile_grid = (N + 15) / 16;
    gemm_bias_mfma<<<tile_grid, 256, 0, stream>>>(x, in_wt, in_b, hb0, N);

    // --- layers (h ping-pong; gather must read pre-update h) ---
    unsigned short* hin = hb0;
    unsigned short* hout = hb1;
    for (int i = 0; i < LAYERS; ++i) {
        float* out = (i == LAYERS - 1) ? (float*)d_out : nullptr;
        agg_mlp_ln<<<tile_grid, 256, 0, stream>>>(hin, rowptr, srcidx, dinv,
                                                  w1t + (size_t)i * DIM * DIM, b1 + (size_t)i * DIM,
                                                  w2t + (size_t)i * DIM * DIM, b2 + (size_t)i * DIM,
                                                  ln_g + (size_t)i * DIM, ln_b + (size_t)i * DIM,
                                                  hout, out, N);
        unsigned short* t = hin; hin = hout; hout = t;
    }
}